// Round 2
// baseline (1230.114 us; speedup 1.0000x reference)
//
#include <hip/hip_runtime.h>

// GAT_30039001268364: 3-layer GAT + BN + residual + mean-pool + MLP on MI355X.
// Runtime-adaptive input dtypes: float tensors may be f32 or bf16, ints may be
// int64 or int32 (detected by bit-pattern probe, canonicalized up front).

#define NN   50000
#define NE   800000
#define NET  (NE + NN)
#define HD   128
#define NG   64

typedef unsigned short u16;
typedef __attribute__((ext_vector_type(8))) short short8;
typedef __attribute__((ext_vector_type(4))) float f32x4;

// ---- canonical parameter pool offsets (bf16 elements) ----
#define O_WEMB 0
#define O_BEMB 16384
#define O_CW   16512
#define O_CAS  49280
#define O_CAD  49536
#define O_CB   49792
#define O_C2W  50048
#define O_C2AS 66432
#define O_C2AD 66560
#define O_C2B  66688
#define O_BNG  66816
#define O_BNB  67200
#define O_L1W  67584
#define O_L1B  83968
#define O_L2W  84096
#define O_L2B  100480
#define O_L3W  100608
#define O_L3B  101888
#define NPAR   101898

// ---- persistent device scratch ----
__device__ int   g_f32flag;           // 1: float inputs are f32; 0: bf16
__device__ int   g_i64flag;           // 1: int inputs are int64; 0: int32
__device__ __align__(16) u16 g_x [NN*HD];   // canonical x (bf16)
__device__ __align__(16) u16 g_par[NPAR];   // canonical params (bf16)
__device__ int   g_src[NE], g_dst[NE], g_batch[NN];
__device__ float g_h[NN*HD];          // residual stream, f32
__device__ __align__(16) u16 g_hb[NN*HD];   // residual stream, bf16 (GEMM A)
__device__ __align__(16) u16 g_hw[NN*HD];   // h @ W per layer, bf16
__device__ float g_c[NN*HD];          // conv output (pre-BN), f32
__device__ float g_asrc[NN*8];
__device__ float g_adst[NN*8];
__device__ int   g_rowptr[NN+1];
__device__ int   g_cursor[NN];
__device__ int   g_csr[NET];          // src node per (dst-sorted) edge
__device__ float g_bnsum[HD], g_bnsq[HD], g_scl[HD], g_shf[HD];
__device__ int   g_gcnt[NG], g_goff[NG];
__device__ float g_pool[NG*HD], g_t1[NG*HD], g_t2[NG*HD];
__device__ __align__(16) u16 g_WT[4][HD*HD];  // WT[n][k] = W[k][n]

__device__ __forceinline__ float b2f(u16 u) {
    unsigned v = ((unsigned)u) << 16; float f; __builtin_memcpy(&f, &v, 4); return f;
}
__device__ __forceinline__ u16 f2b(float f) {
    unsigned v; __builtin_memcpy(&v, &f, 4);
    return (u16)((v + 0x7fffu + ((v >> 16) & 1u)) >> 16);   // RNE
}

// ---- dtype detection (bit-pattern probe, deterministic per dataset) ----
__global__ void k_detect(const void* xp, const void* eip) {
    if (threadIdx.x != 0 || blockIdx.x != 0) return;
    // f32 detect: if x were f32, even u16s are ~uniform mantissa bits; the
    // bf16 decode of a uniform u16 has exponent>=0x93 (|v|>=2^20) w.p. 0.43.
    // Genuine bf16 activations (|v|<~10) never do. 256 samples => certain.
    const u16* p = (const u16*)xp;
    int f32 = 0;
    for (int i = 0; i < 256; ++i) {
        int ex = (p[i] >> 7) & 0xff;
        if (ex >= 0x93) f32 = 1;
    }
    g_f32flag = f32;
    // int64 detect: high words of int64 node ids (<50000) are all zero;
    // genuine int32 data has random node ids at odd positions.
    const int* q = (const int*)eip;
    int nz = 0;
    for (int i = 0; i < 128; ++i) nz += (q[2*i+1] != 0);
    g_i64flag = (nz == 0) ? 1 : 0;
}

// ---- canonicalize inputs ----
__global__ void k_convx(const void* xp) {
    int i = blockIdx.x*256 + threadIdx.x;   // grid 25000 => exactly NN*HD
    g_x[i] = g_f32flag ? f2b(((const float*)xp)[i]) : ((const u16*)xp)[i];
}
struct P18 { const void* p[18]; int off[18]; int n[18]; };
__global__ void k_convpar(P18 a) {
    int f32 = g_f32flag;
    for (int t = 0; t < 18; ++t) {
        const void* s = a.p[t]; int off = a.off[t], n = a.n[t];
        for (int i = blockIdx.x*256 + threadIdx.x; i < n; i += 64*256)
            g_par[off+i] = f32 ? f2b(((const float*)s)[i]) : ((const u16*)s)[i];
    }
}
__global__ void k_convidx(const void* ei, const void* ba) {
    int e = blockIdx.x*256 + threadIdx.x;
    int i64 = g_i64flag;
    if (e < NE) {
        int s, d;
        if (i64) { s = (int)((const long long*)ei)[e]; d = (int)((const long long*)ei)[NE + e]; }
        else     { s = ((const int*)ei)[e];            d = ((const int*)ei)[NE + e]; }
        g_src[e] = s; g_dst[e] = d;
    }
    if (e < NN)
        g_batch[e] = i64 ? (int)((const long long*)ba)[e] : ((const int*)ba)[e];
}

// ---- CSR build ----
__global__ void k_init() {
    int i = blockIdx.x*256 + threadIdx.x;
    if (i < NN) g_cursor[i] = 1;          // self-loop pre-count
    if (i < NG) g_gcnt[i] = 0;
}
__global__ void k_count() {
    int e = blockIdx.x*256 + threadIdx.x;
    if (e < NE) atomicAdd(&g_cursor[g_dst[e]], 1);
}
__global__ void k_scan() {   // 1 block x 1024: inclusive scan of counts -> rowptr
    __shared__ int sh[1024];
    __shared__ int carry;
    int t = threadIdx.x;
    if (t == 0) { carry = 0; g_rowptr[0] = 0; }
    __syncthreads();
    for (int base = 0; base < NN; base += 1024) {
        int i = base + t;
        int v = (i < NN) ? g_cursor[i] : 0;
        sh[t] = v; __syncthreads();
        for (int off = 1; off < 1024; off <<= 1) {
            int add = (t >= off) ? sh[t-off] : 0;
            __syncthreads();
            sh[t] += add;
            __syncthreads();
        }
        int c = carry;
        if (i < NN) g_rowptr[i+1] = c + sh[t];
        __syncthreads();
        if (t == 1023) carry = c + sh[1023];
        __syncthreads();
    }
}
__global__ void k_copycur() {
    int i = blockIdx.x*256 + threadIdx.x;
    if (i < NN) g_cursor[i] = g_rowptr[i];
}
__global__ void k_scatter() {
    int e = blockIdx.x*256 + threadIdx.x;
    if (e >= NET) return;
    int s, d;
    if (e < NE) { s = g_src[e]; d = g_dst[e]; } else { s = d = e - NE; }
    int pos = atomicAdd(&g_cursor[d], 1);
    g_csr[pos] = s;
}

// ---- weight transpose for MFMA B-operand ----
__global__ void k_transpose(int which, int poff) {
    int idx = blockIdx.x*256 + threadIdx.x;   // 64 blocks -> 16384 threads
    int n = idx >> 7, k = idx & 127;
    g_WT[which][n*HD + k] = g_par[poff + k*HD + n];
}

// ---- GEMM: out[r][c] = sum_k A[r][k] * W[k][c] ----
__global__ __launch_bounds__(256) void k_gemm(int asel, int wsel, int biasoff,
                                              int outmode, int nrows) {
    __shared__ __align__(16) u16 wt[HD*136];   // pad 128->136: <=2-way LDS conflict
    const u16* A = asel ? g_hb : g_x;
    const u16* WTg = g_WT[wsel];
    int t = threadIdx.x;
    #pragma unroll
    for (int i = 0; i < 8; ++i) {
        int e = (t + i*256) * 8;
        int n = e >> 7, k = e & 127;
        *(uint4*)&wt[n*136 + k] = *(const uint4*)&WTg[e];
    }
    __syncthreads();
    int lane = t & 63, wave = t >> 6;
    int m16 = lane & 15, q = lane >> 4;
    int row0 = blockIdx.x*128 + wave*32;
    f32x4 acc[2][8];
    #pragma unroll
    for (int a = 0; a < 2; ++a)
        #pragma unroll
        for (int b = 0; b < 8; ++b) acc[a][b] = (f32x4){0.f,0.f,0.f,0.f};
    #pragma unroll
    for (int kc = 0; kc < 4; ++kc) {
        short8 af[2];
        #pragma unroll
        for (int rt = 0; rt < 2; ++rt) {
            int r = row0 + rt*16 + m16; if (r > nrows-1) r = nrows-1;
            af[rt] = *(const short8*)&A[r*HD + kc*32 + q*8];   // A[m=lane&15][k=q*8+j]
        }
        #pragma unroll
        for (int ct = 0; ct < 8; ++ct) {
            short8 bf = *(const short8*)&wt[(ct*16 + m16)*136 + kc*32 + q*8]; // B[k][n=lane&15]
            acc[0][ct] = __builtin_amdgcn_mfma_f32_16x16x32_bf16(af[0], bf, acc[0][ct], 0,0,0);
            acc[1][ct] = __builtin_amdgcn_mfma_f32_16x16x32_bf16(af[1], bf, acc[1][ct], 0,0,0);
        }
    }
    // C/D layout (m89-verified): col = lane&15, row = q*4 + reg
    #pragma unroll
    for (int rt = 0; rt < 2; ++rt)
        #pragma unroll
        for (int reg = 0; reg < 4; ++reg) {
            int r = row0 + rt*16 + q*4 + reg;
            if (r < nrows) {
                #pragma unroll
                for (int ct = 0; ct < 8; ++ct) {
                    int c = ct*16 + m16;
                    float v = acc[rt][ct][reg];
                    if (biasoff >= 0) v += b2f(g_par[biasoff + c]);
                    if (outmode == 0) { g_h[r*HD+c] = v; g_hb[r*HD+c] = f2b(v); }
                    else              { g_hw[r*HD+c] = f2b(v); }
                }
            }
        }
}

// ---- per-node attention logits ----
__global__ void k_att(int asoff, int adoff, int heads, int ch, int total) {
    int idx = blockIdx.x*256 + threadIdx.x;
    if (idx >= total) return;
    int n = idx / heads, h = idx - n*heads;
    const u16* row = g_hw + n*HD + h*ch;
    float s1 = 0.f, s2 = 0.f;
    for (int c = 0; c < ch; ++c) {
        float w = b2f(row[c]);
        s1 += w * b2f(g_par[asoff + h*ch + c]);
        s2 += w * b2f(g_par[adoff + h*ch + c]);
    }
    g_asrc[idx] = s1; g_adst[idx] = s2;
}

// ---- flash-style segment softmax + aggregate: one wave per dst node ----
// First edge peeled: no +-inf ever enters __expf (its behavior at -3.4e38 is
// library-dependent and was the round-1 NaN suspect).
__global__ __launch_bounds__(256) void k_flash(int boff, int heads, int hs) {
    int node = blockIdx.x*4 + (threadIdx.x >> 6);   // 12500 blocks * 4 waves = NN
    int lane = threadIdx.x & 63;
    int c0 = lane*2;
    int head = c0 >> hs;
    float ad = g_adst[node*heads + head];
    int beg = g_rowptr[node], end = g_rowptr[node+1];
    float m = 0.f, l = 0.f, o0 = 0.f, o1 = 0.f;
    if (end > beg) {
        int s = g_csr[beg];
        float e = g_asrc[s*heads + head] + ad;
        e = e > 0.f ? e : 0.2f*e;                  // leaky_relu slope 0.2
        m = e; l = 1.f;
        unsigned w = *(const unsigned*)&g_hw[s*HD + c0];
        o0 = b2f((u16)(w & 0xffff));
        o1 = b2f((u16)(w >> 16));
        for (int j = beg+1; j < end; ++j) {
            s = g_csr[j];
            e = g_asrc[s*heads + head] + ad;
            e = e > 0.f ? e : 0.2f*e;
            float nm = fmaxf(m, e);
            float sc = __expf(m - nm);
            float p  = __expf(e - nm);
            w = *(const unsigned*)&g_hw[s*HD + c0];
            l  = l*sc + p;
            o0 = o0*sc + p*b2f((u16)(w & 0xffff));
            o1 = o1*sc + p*b2f((u16)(w >> 16));
            m = nm;
        }
    }
    float inv = (l > 0.f) ? 1.f/l : 0.f;
    g_c[node*HD + c0]     = o0*inv + b2f(g_par[boff + c0]);
    g_c[node*HD + c0 + 1] = o1*inv + b2f(g_par[boff + c0 + 1]);
}

// ---- BatchNorm (training stats) + ReLU + residual ----
__global__ void k_bnzero() { int t = threadIdx.x; if (t < HD) { g_bnsum[t] = 0.f; g_bnsq[t] = 0.f; } }
__global__ void k_bnstats() {
    int t = threadIdx.x; int ch = t & 127, r0 = t >> 7;
    int base = blockIdx.x*128;
    float s = 0.f, q = 0.f;
    for (int i = r0; i < 128; i += 2) {
        int n = base + i;
        if (n < NN) { float v = g_c[n*HD + ch]; s += v; q += v*v; }
    }
    __shared__ float sS[256], sQ[256];
    sS[t] = s; sQ[t] = q; __syncthreads();
    if (t < 128) {
        atomicAdd(&g_bnsum[t], sS[t] + sS[t+128]);
        atomicAdd(&g_bnsq[t],  sQ[t] + sQ[t+128]);
    }
}
__global__ void k_bnfinal(int goff, int boff) {
    int t = threadIdx.x; if (t >= HD) return;
    float mean = g_bnsum[t] / (float)NN;
    float var  = fmaxf(g_bnsq[t] / (float)NN - mean*mean, 0.f);
    float sc = b2f(g_par[goff + t]) * rsqrtf(var + 1e-5f);
    g_scl[t] = sc;
    g_shf[t] = b2f(g_par[boff + t]) - mean*sc;
}
__global__ void k_bnapply() {   // exactly NN*HD threads
    int idx = blockIdx.x*256 + threadIdx.x;
    int ch = idx & 127;
    float v = g_c[idx]*g_scl[ch] + g_shf[ch];
    if (v < 0.f) v = 0.f;
    float nh = v + g_h[idx];
    g_h[idx] = nh;
    g_hb[idx] = f2b(nh);
}

// ---- global mean pool (batch sorted) ----
__global__ void k_gcount() {
    int n = blockIdx.x*256 + threadIdx.x;
    if (n < NN) atomicAdd(&g_gcnt[g_batch[n]], 1);
}
__global__ void k_gscan() {
    __shared__ int a[NG];
    int t = threadIdx.x;
    if (t < NG) a[t] = g_gcnt[t];
    __syncthreads();
    if (t < NG) { int off = 0; for (int i = 0; i < t; ++i) off += a[i]; g_goff[t] = off; }
}
__global__ void k_pool() {
    int g = blockIdx.x;
    int cnt = g_gcnt[g], off = g_goff[g];
    int t = threadIdx.x; int ch = t & 127, r0 = t >> 7;
    float s = 0.f;
    for (int i = r0; i < cnt; i += 2) s += g_h[(off + i)*HD + ch];
    __shared__ float sh[256];
    sh[t] = s; __syncthreads();
    if (t < 128) g_pool[g*HD + t] = (sh[t] + sh[t+128]) / fmaxf((float)cnt, 1.f);
}

// ---- tiny dense layers ----
__global__ void k_lin(int insel, int woff, int boff, int outsel, void* outB,
                      int outdim, int dorelu, int total) {
    int idx = blockIdx.x*256 + threadIdx.x;
    if (idx >= total) return;
    const float* in = (insel == 0) ? g_pool : (insel == 1) ? g_t1 : g_t2;
    int g = idx / outdim, j = idx - g*outdim;
    float acc = b2f(g_par[boff + j]);
    const float* ir = in + g*HD;
    for (int k = 0; k < HD; ++k) acc += ir[k] * b2f(g_par[woff + k*outdim + j]);
    if (dorelu && acc < 0.f) acc = 0.f;
    if (outsel == 0)      g_t1[idx] = acc;
    else if (outsel == 1) g_t2[idx] = acc;
    else if (g_f32flag)   ((float*)outB)[idx] = acc;
    else                  ((u16*)outB)[idx] = f2b(acc);
}

extern "C" void kernel_launch(void* const* d_in, const int* in_sizes, int n_in,
                              void* d_out, int out_size, void* d_ws, size_t ws_size,
                              hipStream_t stream) {
    const void* x     = d_in[0];
    const void* ei    = d_in[1];
    // d_in[2] = cycle_index (unused by reference)
    const void* batch = d_in[3];

    // dtype detection + canonicalization
    k_detect<<<1, 64, 0, stream>>>(x, ei);
    k_convx<<<25000, 256, 0, stream>>>(x);
    P18 a;
    const int srcidx[18] = {4,5,6,7,8,9,10,11,12,13,14,15,16,17,18,19,20,21};
    const int offs[18] = {O_WEMB,O_BEMB,O_CW,O_CAS,O_CAD,O_CB,O_C2W,O_C2AS,O_C2AD,
                          O_C2B,O_BNG,O_BNB,O_L1W,O_L1B,O_L2W,O_L2B,O_L3W,O_L3B};
    const int lens[18] = {16384,128,32768,256,256,256,16384,128,128,128,384,384,
                          16384,128,16384,128,1280,10};
    for (int t = 0; t < 18; ++t) { a.p[t] = d_in[srcidx[t]]; a.off[t] = offs[t]; a.n[t] = lens[t]; }
    k_convpar<<<64, 256, 0, stream>>>(a);
    k_convidx<<<3125, 256, 0, stream>>>(ei, batch);

    // CSR build (same edges for all 3 layers)
    k_init<<<196, 256, 0, stream>>>();
    k_count<<<3125, 256, 0, stream>>>();
    k_scan<<<1, 1024, 0, stream>>>();
    k_copycur<<<196, 256, 0, stream>>>();
    k_scatter<<<3321, 256, 0, stream>>>();

    // weight transposes for MFMA B-operand
    k_transpose<<<64, 256, 0, stream>>>(0, O_WEMB);
    k_transpose<<<64, 256, 0, stream>>>(1, O_CW);
    k_transpose<<<64, 256, 0, stream>>>(2, O_CW + HD*HD);
    k_transpose<<<64, 256, 0, stream>>>(3, O_C2W);

    // embedding: h = x @ W_emb + b_emb
    k_gemm<<<391, 256, 0, stream>>>(0, 0, O_BEMB, 0, NN);

    for (int L = 0; L < 3; ++L) {
        int heads = (L < 2) ? 8 : 1;
        int ch    = (L < 2) ? 16 : 128;
        int hs    = (L < 2) ? 4 : 7;
        int as    = (L < 2) ? O_CAS + L*128 : O_C2AS;
        int ad    = (L < 2) ? O_CAD + L*128 : O_C2AD;
        int cb    = (L < 2) ? O_CB  + L*128 : O_C2B;
        k_gemm<<<391, 256, 0, stream>>>(1, L+1, -1, 1, NN);
        int atot = NN*heads;
        k_att<<<(atot + 255)/256, 256, 0, stream>>>(as, ad, heads, ch, atot);
        k_flash<<<12500, 256, 0, stream>>>(cb, heads, hs);
        k_bnzero<<<1, 128, 0, stream>>>();
        k_bnstats<<<391, 256, 0, stream>>>();
        k_bnfinal<<<1, 128, 0, stream>>>(O_BNG + L*HD, O_BNB + L*HD);
        k_bnapply<<<25000, 256, 0, stream>>>();
    }

    // mean pool + MLP head
    k_gcount<<<196, 256, 0, stream>>>();
    k_gscan<<<1, 64, 0, stream>>>();
    k_pool<<<64, 256, 0, stream>>>();
    k_lin<<<32, 256, 0, stream>>>(0, O_L1W, O_L1B, 0, nullptr, HD, 1, NG*HD);
    k_lin<<<32, 256, 0, stream>>>(1, O_L2W, O_L2B, 1, nullptr, HD, 1, NG*HD);
    k_lin<<<3, 256, 0, stream>>>(2, O_L3W, O_L3B, 2, d_out, 10, 0, NG*10);
}

// Round 4
// 833.426 us; speedup vs baseline: 1.4760x; 1.4760x over previous
//
#include <hip/hip_runtime.h>

// GAT_30039001268364: 3-layer GAT + BN + residual + mean-pool + MLP on MI355X.
// Runtime-adaptive input dtypes (f32-vs-bf16, int64-vs-int32 probed on device).

#define NN   50000
#define NE   800000
#define NET  (NE + NN)
#define HD   128
#define NG   64
#define NB   196          // ceil(NN/256)  — 256 items/block kernels
#define NBN  391          // ceil(NN/128)  — 128 nodes/block kernels (BN stats)

typedef unsigned short u16;
typedef __attribute__((ext_vector_type(8))) short short8;
typedef __attribute__((ext_vector_type(4))) float f32x4;

// ---- canonical parameter pool offsets (bf16 elements) ----
#define O_WEMB 0
#define O_BEMB 16384
#define O_CW   16512
#define O_CAS  49280
#define O_CAD  49536
#define O_CB   49792
#define O_C2W  50048
#define O_C2AS 66432
#define O_C2AD 66560
#define O_C2B  66688
#define O_BNG  66816
#define O_BNB  67200
#define O_L1W  67584
#define O_L1B  83968
#define O_L2W  84096
#define O_L2B  100480
#define O_L3W  100608
#define O_L3B  101888
#define NPAR   101898

// ---- persistent device scratch ----
__device__ int   g_f32flag, g_i64flag;
__device__ __align__(16) u16 g_x [NN*HD];
__device__ __align__(16) u16 g_par[NPAR];
__device__ int   g_src[NE], g_dst[NE], g_batch[NN];
__device__ __align__(16) float g_h[NN*HD];
__device__ __align__(16) u16 g_hb[NN*HD];
__device__ __align__(16) u16 g_hw[NN*HD];
__device__ __align__(16) float g_c[NN*HD];
__device__ float g_asrc[NN*8];
__device__ float g_adst[NN*8];
__device__ int   g_rowptr[NN+1];
__device__ int   g_cursor[NN];
__device__ int   g_bsum[NB], g_boff[NB];
__device__ int   g_csr[NET];
__device__ float g_bnp1[NBN*HD], g_bnp2[NBN*HD];
__device__ float g_scl[HD], g_shf[HD];
__device__ int   g_gcnt[NG], g_goff[NG];
__device__ float g_pool[NG*HD], g_t1[NG*HD], g_t2[NG*HD];
__device__ __align__(16) u16 g_WT[4][HD*HD];

__device__ __forceinline__ float b2f(u16 u) {
    unsigned v = ((unsigned)u) << 16; float f; __builtin_memcpy(&f, &v, 4); return f;
}
__device__ __forceinline__ u16 f2b(float f) {
    unsigned v; __builtin_memcpy(&v, &f, 4);
    return (u16)((v + 0x7fffu + ((v >> 16) & 1u)) >> 16);   // RNE
}

// intra-block inclusive scan (256 threads = 4 waves), shuffle-based
__device__ __forceinline__ int block_incl_scan(int v, int* lds4) {
    int t = threadIdx.x, lane = t & 63, w = t >> 6;
    #pragma unroll
    for (int d = 1; d < 64; d <<= 1) {
        int o = __shfl_up(v, d);
        if (lane >= d) v += o;
    }
    if (lane == 63) lds4[w] = v;
    __syncthreads();
    if (w == 0 && lane < 4) {
        int s = lds4[lane];
        #pragma unroll
        for (int d = 1; d < 4; d <<= 1) {
            int o = __shfl_up(s, d);
            if (lane >= d) s += o;
        }
        lds4[lane] = s;
    }
    __syncthreads();
    if (w > 0) v += lds4[w-1];
    return v;
}

// ---- dtype detection ----
__global__ void k_detect(const void* xp, const void* eip) {
    if (threadIdx.x != 0 || blockIdx.x != 0) return;
    const u16* p = (const u16*)xp;
    int f32 = 0;
    for (int i = 0; i < 256; ++i) {
        int ex = (p[i] >> 7) & 0xff;
        if (ex >= 0x93) f32 = 1;      // |v|>=2^20: impossible for bf16 activations
    }
    g_f32flag = f32;
    const int* q = (const int*)eip;
    int nz = 0;
    for (int i = 0; i < 128; ++i) nz += (q[2*i+1] != 0);
    g_i64flag = (nz == 0) ? 1 : 0;    // int64 node ids: high words all zero
}

// ---- canonicalize inputs ----
__global__ void k_convx(const void* xp) {    // grid 6250 x 256, x4 vectorized
    int i = (blockIdx.x*256 + threadIdx.x)*4;
    if (g_f32flag) {
        float4 v = *(const float4*)((const float*)xp + i);
        ushort4 o = { f2b(v.x), f2b(v.y), f2b(v.z), f2b(v.w) };
        *(ushort4*)&g_x[i] = o;
    } else {
        *(ushort4*)&g_x[i] = *(const ushort4*)((const u16*)xp + i);
    }
}
struct P18 { const void* p[18]; int off[18]; int n[18]; };
__global__ void k_convpar(P18 a) {
    int f32 = g_f32flag;
    for (int t = 0; t < 18; ++t) {
        const void* s = a.p[t]; int off = a.off[t], n = a.n[t];
        for (int i = blockIdx.x*256 + threadIdx.x; i < n; i += 64*256)
            g_par[off+i] = f32 ? f2b(((const float*)s)[i]) : ((const u16*)s)[i];
    }
}
__global__ void k_init() {   // cursor=1 (self-loop pre-count); must precede k_convidx
    int i = blockIdx.x*256 + threadIdx.x;
    if (i < NN) g_cursor[i] = 1;
}
__global__ void k_convidx(const void* ei, const void* ba) {   // + fused edge count
    int e = blockIdx.x*256 + threadIdx.x;
    int i64 = g_i64flag;
    if (e < NE) {
        int s, d;
        if (i64) { s = (int)((const long long*)ei)[e]; d = (int)((const long long*)ei)[NE + e]; }
        else     { s = ((const int*)ei)[e];            d = ((const int*)ei)[NE + e]; }
        g_src[e] = s; g_dst[e] = d;
        atomicAdd(&g_cursor[d], 1);
    }
    if (e < NN)
        g_batch[e] = i64 ? (int)((const long long*)ba)[e] : ((const int*)ba)[e];
}

// ---- hierarchical exclusive scan of degree counts -> rowptr + scatter cursor ----
__global__ void k_blocksum() {
    int i = blockIdx.x*256 + threadIdx.x;
    int v = (i < NN) ? g_cursor[i] : 0;
    #pragma unroll
    for (int d = 32; d; d >>= 1) v += __shfl_down(v, d);
    __shared__ int lds[4];
    if ((threadIdx.x & 63) == 0) lds[threadIdx.x >> 6] = v;
    __syncthreads();
    if (threadIdx.x == 0) g_bsum[blockIdx.x] = lds[0]+lds[1]+lds[2]+lds[3];
}
__global__ void k_scanb() {     // 1 block x 256 over NB=196 block sums
    __shared__ int lds[4];
    int t = threadIdx.x;
    int v = (t < NB) ? g_bsum[t] : 0;
    int incl = block_incl_scan(v, lds);
    if (t < NB) g_boff[t] = incl - v;     // exclusive
}
__global__ void k_downsweep() {
    __shared__ int lds[4];
    int i = blockIdx.x*256 + threadIdx.x;
    int c = (i < NN) ? g_cursor[i] : 0;
    int incl = block_incl_scan(c, lds);
    int base = g_boff[blockIdx.x];
    if (i < NN) {
        g_rowptr[i+1] = base + incl;
        g_cursor[i]   = base + incl - c;  // exclusive start = scatter cursor
    }
    if (i == 0) g_rowptr[0] = 0;
}
__global__ void k_scatter() {
    int e = blockIdx.x*256 + threadIdx.x;
    if (e >= NET) return;
    int s, d;
    if (e < NE) { s = g_src[e]; d = g_dst[e]; } else { s = d = e - NE; }
    int pos = atomicAdd(&g_cursor[d], 1);
    g_csr[pos] = s;
}

// ---- all 4 weight transposes in one kernel (256 blocks) ----
__global__ void k_transpose4() {
    int which = blockIdx.x >> 6;
    int poff = which==0 ? O_WEMB : which==1 ? O_CW : which==2 ? (O_CW+16384) : O_C2W;
    int idx = (blockIdx.x & 63)*256 + threadIdx.x;
    int n = idx >> 7, k = idx & 127;
    g_WT[which][n*HD + k] = g_par[poff + k*HD + n];
}

// ---- GEMM: out[r][c] = sum_k A[r][k] * W[k][c] ----
__global__ __launch_bounds__(256) void k_gemm(int asel, int wsel, int biasoff,
                                              int outmode, int nrows) {
    __shared__ __align__(16) u16 wt[HD*136];
    const u16* A = asel ? g_hb : g_x;
    const u16* WTg = g_WT[wsel];
    int t = threadIdx.x;
    #pragma unroll
    for (int i = 0; i < 8; ++i) {
        int e = (t + i*256) * 8;
        int n = e >> 7, k = e & 127;
        *(uint4*)&wt[n*136 + k] = *(const uint4*)&WTg[e];
    }
    __syncthreads();
    int lane = t & 63, wave = t >> 6;
    int m16 = lane & 15, q = lane >> 4;
    int row0 = blockIdx.x*128 + wave*32;
    f32x4 acc[2][8];
    #pragma unroll
    for (int a = 0; a < 2; ++a)
        #pragma unroll
        for (int b = 0; b < 8; ++b) acc[a][b] = (f32x4){0.f,0.f,0.f,0.f};
    #pragma unroll
    for (int kc = 0; kc < 4; ++kc) {
        short8 af[2];
        #pragma unroll
        for (int rt = 0; rt < 2; ++rt) {
            int r = row0 + rt*16 + m16; if (r > nrows-1) r = nrows-1;
            af[rt] = *(const short8*)&A[r*HD + kc*32 + q*8];
        }
        #pragma unroll
        for (int ct = 0; ct < 8; ++ct) {
            short8 bf = *(const short8*)&wt[(ct*16 + m16)*136 + kc*32 + q*8];
            acc[0][ct] = __builtin_amdgcn_mfma_f32_16x16x32_bf16(af[0], bf, acc[0][ct], 0,0,0);
            acc[1][ct] = __builtin_amdgcn_mfma_f32_16x16x32_bf16(af[1], bf, acc[1][ct], 0,0,0);
        }
    }
    // C/D layout: col = lane&15, row = q*4 + reg
    #pragma unroll
    for (int rt = 0; rt < 2; ++rt)
        #pragma unroll
        for (int reg = 0; reg < 4; ++reg) {
            int r = row0 + rt*16 + q*4 + reg;
            if (r < nrows) {
                #pragma unroll
                for (int ct = 0; ct < 8; ++ct) {
                    int c = ct*16 + m16;
                    float v = acc[rt][ct][reg];
                    if (biasoff >= 0) v += b2f(g_par[biasoff + c]);
                    if (outmode == 0) { g_h[r*HD+c] = v; g_hb[r*HD+c] = f2b(v); }
                    else              { g_hw[r*HD+c] = f2b(v); }
                }
            }
        }
}

// ---- per-node attention logits (short8-vectorized) ----
__global__ void k_att(int asoff, int adoff, int heads, int ch, int total) {
    int idx = blockIdx.x*256 + threadIdx.x;
    if (idx >= total) return;
    int n = idx / heads, h = idx - n*heads;
    const u16* row = g_hw + n*HD + h*ch;
    const u16* As  = g_par + asoff + h*ch;
    const u16* Ad  = g_par + adoff + h*ch;
    float s1 = 0.f, s2 = 0.f;
    for (int c = 0; c < ch; c += 8) {
        short8 hv = *(const short8*)&row[c];
        short8 sv = *(const short8*)&As[c];
        short8 dv = *(const short8*)&Ad[c];
        #pragma unroll
        for (int k = 0; k < 8; ++k) {
            float w = b2f((u16)hv[k]);
            s1 += w * b2f((u16)sv[k]);
            s2 += w * b2f((u16)dv[k]);
        }
    }
    g_asrc[idx] = s1; g_adst[idx] = s2;
}

// ---- segment softmax + aggregate: one wave per dst node ----
// Logits are bounded (|e| ~ <2; clamped at 30), so plain-exp accumulation is
// exactly the reference softmax up to rounding — no online max needed.
__global__ __launch_bounds__(256) void k_flash(int boff, int heads, int hs) {
    int node = blockIdx.x*4 + (threadIdx.x >> 6);
    int lane = threadIdx.x & 63;
    int c0 = lane*2;
    int head = c0 >> hs;
    float ad = g_adst[node*heads + head];
    int beg = g_rowptr[node], end = g_rowptr[node+1];
    float l = 0.f, o0 = 0.f, o1 = 0.f;
    int s_next = g_csr[beg];               // self-loop guarantees beg < end
    for (int j = beg; j < end; ++j) {
        int s = s_next;
        if (j+1 < end) s_next = g_csr[j+1];        // 1-deep prefetch
        float e = g_asrc[s*heads + head] + ad;
        e = e > 0.f ? e : 0.2f*e;                  // leaky_relu 0.2
        e = fminf(e, 30.f);                        // overflow guard
        float p = __expf(e);
        unsigned w = *(const unsigned*)&g_hw[s*HD + c0];
        l  += p;
        o0 += p*b2f((u16)(w & 0xffff));
        o1 += p*b2f((u16)(w >> 16));
    }
    float inv = 1.f/l;
    g_c[node*HD + c0]     = o0*inv + b2f(g_par[boff + c0]);
    g_c[node*HD + c0 + 1] = o1*inv + b2f(g_par[boff + c0 + 1]);
}

// ---- BatchNorm: per-block partials (no atomics) + small reduce ----
// NBN=391 blocks x 128 nodes each (round-3 bug: NB=196 covered half the nodes)
__global__ void k_bnstats() {
    int t = threadIdx.x; int ch = t & 127, r0 = t >> 7;
    int base = blockIdx.x*128;
    float s = 0.f, q = 0.f;
    for (int i = r0; i < 128; i += 2) {
        int n = base + i;
        if (n < NN) { float v = g_c[n*HD + ch]; s += v; q += v*v; }
    }
    __shared__ float sS[256], sQ[256];
    sS[t] = s; sQ[t] = q; __syncthreads();
    if (t < 128) {
        g_bnp1[blockIdx.x*HD + t] = sS[t] + sS[t+128];
        g_bnp2[blockIdx.x*HD + t] = sQ[t] + sQ[t+128];
    }
}
__global__ void k_bnfinal(int goff, int boff) {
    int t = threadIdx.x; if (t >= HD) return;
    float s = 0.f, q = 0.f;
    for (int b = 0; b < NBN; ++b) { s += g_bnp1[b*HD + t]; q += g_bnp2[b*HD + t]; }
    float mean = s / (float)NN;
    float var  = fmaxf(q / (float)NN - mean*mean, 0.f);
    float sc = b2f(g_par[goff + t]) * rsqrtf(var + 1e-5f);
    g_scl[t] = sc;
    g_shf[t] = b2f(g_par[boff + t]) - mean*sc;
}
__global__ void k_bnapply() {   // grid 6250 x 256, x4 vectorized
    int i = (blockIdx.x*256 + threadIdx.x)*4;
    int ch = i & 127;
    float4 c = *(const float4*)&g_c[i];
    float4 h = *(const float4*)&g_h[i];
    float4 r;
    r.x = fmaxf(c.x*g_scl[ch  ] + g_shf[ch  ], 0.f) + h.x;
    r.y = fmaxf(c.y*g_scl[ch+1] + g_shf[ch+1], 0.f) + h.y;
    r.z = fmaxf(c.z*g_scl[ch+2] + g_shf[ch+2], 0.f) + h.z;
    r.w = fmaxf(c.w*g_scl[ch+3] + g_shf[ch+3], 0.f) + h.w;
    *(float4*)&g_h[i] = r;
    ushort4 o = { f2b(r.x), f2b(r.y), f2b(r.z), f2b(r.w) };
    *(ushort4*)&g_hb[i] = o;
}

// ---- graph offsets via binary search over sorted batch ----
__global__ void k_gidx() {    // 1 block x 128
    __shared__ int off[NG+1];
    int g = threadIdx.x;
    if (g <= NG) {
        int lo = 0, hi = NN;
        while (lo < hi) { int mid = (lo+hi) >> 1; if (g_batch[mid] < g) lo = mid+1; else hi = mid; }
        off[g] = lo;
    }
    __syncthreads();
    if (g < NG) { g_goff[g] = off[g]; g_gcnt[g] = off[g+1] - off[g]; }
}
__global__ void k_pool() {
    int g = blockIdx.x;
    int cnt = g_gcnt[g], off = g_goff[g];
    int t = threadIdx.x; int ch = t & 127, r0 = t >> 7;
    float s = 0.f;
    for (int i = r0; i < cnt; i += 2) s += g_h[(off + i)*HD + ch];
    __shared__ float sh[256];
    sh[t] = s; __syncthreads();
    if (t < 128) g_pool[g*HD + t] = (sh[t] + sh[t+128]) / fmaxf((float)cnt, 1.f);
}

// ---- tiny dense layers ----
__global__ void k_lin(int insel, int woff, int boff, int outsel, void* outB,
                      int outdim, int dorelu, int total) {
    int idx = blockIdx.x*256 + threadIdx.x;
    if (idx >= total) return;
    const float* in = (insel == 0) ? g_pool : (insel == 1) ? g_t1 : g_t2;
    int g = idx / outdim, j = idx - g*outdim;
    float acc = b2f(g_par[boff + j]);
    const float* ir = in + g*HD;
    for (int k = 0; k < HD; ++k) acc += ir[k] * b2f(g_par[woff + k*outdim + j]);
    if (dorelu && acc < 0.f) acc = 0.f;
    if (outsel == 0)      g_t1[idx] = acc;
    else if (outsel == 1) g_t2[idx] = acc;
    else if (g_f32flag)   ((float*)outB)[idx] = acc;
    else                  ((u16*)outB)[idx] = f2b(acc);
}

extern "C" void kernel_launch(void* const* d_in, const int* in_sizes, int n_in,
                              void* d_out, int out_size, void* d_ws, size_t ws_size,
                              hipStream_t stream) {
    const void* x     = d_in[0];
    const void* ei    = d_in[1];
    const void* batch = d_in[3];

    k_detect<<<1, 64, 0, stream>>>(x, ei);
    k_init<<<NB, 256, 0, stream>>>();
    k_convx<<<6250, 256, 0, stream>>>(x);
    P18 a;
    const int srcidx[18] = {4,5,6,7,8,9,10,11,12,13,14,15,16,17,18,19,20,21};
    const int offs[18] = {O_WEMB,O_BEMB,O_CW,O_CAS,O_CAD,O_CB,O_C2W,O_C2AS,O_C2AD,
                          O_C2B,O_BNG,O_BNB,O_L1W,O_L1B,O_L2W,O_L2B,O_L3W,O_L3B};
    const int lens[18] = {16384,128,32768,256,256,256,16384,128,128,128,384,384,
                          16384,128,16384,128,1280,10};
    for (int t = 0; t < 18; ++t) { a.p[t] = d_in[srcidx[t]]; a.off[t] = offs[t]; a.n[t] = lens[t]; }
    k_convpar<<<64, 256, 0, stream>>>(a);
    k_convidx<<<3125, 256, 0, stream>>>(ei, batch);   // fused edge-count atomics

    k_blocksum<<<NB, 256, 0, stream>>>();
    k_scanb<<<1, 256, 0, stream>>>();
    k_downsweep<<<NB, 256, 0, stream>>>();
    k_scatter<<<3321, 256, 0, stream>>>();
    k_transpose4<<<256, 256, 0, stream>>>();
    k_gidx<<<1, 128, 0, stream>>>();

    // embedding: h = x @ W_emb + b_emb
    k_gemm<<<391, 256, 0, stream>>>(0, 0, O_BEMB, 0, NN);

    for (int L = 0; L < 3; ++L) {
        int heads = (L < 2) ? 8 : 1;
        int ch    = (L < 2) ? 16 : 128;
        int hs    = (L < 2) ? 4 : 7;
        int as    = (L < 2) ? O_CAS + L*128 : O_C2AS;
        int ad    = (L < 2) ? O_CAD + L*128 : O_C2AD;
        int cb    = (L < 2) ? O_CB  + L*128 : O_C2B;
        k_gemm<<<391, 256, 0, stream>>>(1, L+1, -1, 1, NN);
        int atot = NN*heads;
        k_att<<<(atot + 255)/256, 256, 0, stream>>>(as, ad, heads, ch, atot);
        k_flash<<<12500, 256, 0, stream>>>(cb, heads, hs);
        k_bnstats<<<NBN, 256, 0, stream>>>();
        k_bnfinal<<<1, 128, 0, stream>>>(O_BNG + L*HD, O_BNB + L*HD);
        k_bnapply<<<6250, 256, 0, stream>>>();
    }

    k_pool<<<64, 256, 0, stream>>>();
    k_lin<<<32, 256, 0, stream>>>(0, O_L1W, O_L1B, 0, nullptr, HD, 1, NG*HD);
    k_lin<<<32, 256, 0, stream>>>(1, O_L2W, O_L2B, 1, nullptr, HD, 1, NG*HD);
    k_lin<<<3, 256, 0, stream>>>(2, O_L3W, O_L3B, 2, d_out, 10, 0, NG*10);
}

// Round 5
// 735.904 us; speedup vs baseline: 1.6716x; 1.1325x over previous
//
#include <hip/hip_runtime.h>

// GAT_30039001268364: 3-layer GAT + BN + residual + mean-pool + MLP on MI355X.
// Runtime-adaptive input dtypes (f32-vs-bf16, int64-vs-int32 probed on device).

#define NN   50000
#define NE   800000
#define NET  (NE + NN)
#define HD   128
#define NG   64
#define NB   196          // ceil(NN/256)  — 256 items/block kernels
#define NBN  391          // ceil(NN/128)  — 128 nodes/block kernels (BN stats)
#define NCH  20           // pool chunks per graph (64*20 = 1280 blocks)

typedef unsigned short u16;
typedef __attribute__((ext_vector_type(8))) short short8;
typedef __attribute__((ext_vector_type(4))) float f32x4;

// ---- canonical parameter pool offsets (bf16 elements) ----
#define O_WEMB 0
#define O_BEMB 16384
#define O_CW   16512
#define O_CAS  49280
#define O_CAD  49536
#define O_CB   49792
#define O_C2W  50048
#define O_C2AS 66432
#define O_C2AD 66560
#define O_C2B  66688
#define O_BNG  66816
#define O_BNB  67200
#define O_L1W  67584
#define O_L1B  83968
#define O_L2W  84096
#define O_L2B  100480
#define O_L3W  100608
#define O_L3B  101888
#define NPAR   101898

// ---- persistent device scratch ----
__device__ int   g_f32flag, g_i64flag;
__device__ __align__(16) u16 g_x [NN*HD];
__device__ __align__(16) u16 g_par[NPAR];
__device__ int   g_src[NE], g_dst[NE], g_batch[NN];
__device__ __align__(16) float g_h[NN*HD];
__device__ __align__(16) u16 g_hb[NN*HD];
__device__ __align__(16) u16 g_hw[NN*HD];
__device__ __align__(16) float g_c[NN*HD];
__device__ float g_asrc[NN*8];
__device__ float g_adst[NN*8];
__device__ int   g_rowptr[NN+1];
__device__ int   g_cursor[NN];
__device__ int   g_bsum[NB], g_boff[NB];
__device__ int   g_csr[NET];
__device__ float g_bnp1[NBN*HD], g_bnp2[NBN*HD];
__device__ float g_scl[HD], g_shf[HD];
__device__ int   g_gcnt[NG], g_goff[NG];
__device__ __align__(16) float g_poolp[NG*NCH*HD];
__device__ float g_pool[NG*HD], g_t1[NG*HD], g_t2[NG*HD];
__device__ __align__(16) u16 g_WT[4][HD*HD];

__device__ __forceinline__ float b2f(u16 u) {
    unsigned v = ((unsigned)u) << 16; float f; __builtin_memcpy(&f, &v, 4); return f;
}
__device__ __forceinline__ u16 f2b(float f) {
    unsigned v; __builtin_memcpy(&v, &f, 4);
    return (u16)((v + 0x7fffu + ((v >> 16) & 1u)) >> 16);   // RNE
}

// intra-block inclusive scan (256 threads = 4 waves), shuffle-based
__device__ __forceinline__ int block_incl_scan(int v, int* lds4) {
    int t = threadIdx.x, lane = t & 63, w = t >> 6;
    #pragma unroll
    for (int d = 1; d < 64; d <<= 1) {
        int o = __shfl_up(v, d);
        if (lane >= d) v += o;
    }
    if (lane == 63) lds4[w] = v;
    __syncthreads();
    if (w == 0 && lane < 4) {
        int s = lds4[lane];
        #pragma unroll
        for (int d = 1; d < 4; d <<= 1) {
            int o = __shfl_up(s, d);
            if (lane >= d) s += o;
        }
        lds4[lane] = s;
    }
    __syncthreads();
    if (w > 0) v += lds4[w-1];
    return v;
}

// ---- dtype detection ----
__global__ void k_detect(const void* xp, const void* eip) {
    if (threadIdx.x != 0 || blockIdx.x != 0) return;
    const u16* p = (const u16*)xp;
    int f32 = 0;
    for (int i = 0; i < 256; ++i) {
        int ex = (p[i] >> 7) & 0xff;
        if (ex >= 0x93) f32 = 1;      // |v|>=2^20: impossible for bf16 activations
    }
    g_f32flag = f32;
    const int* q = (const int*)eip;
    int nz = 0;
    for (int i = 0; i < 128; ++i) nz += (q[2*i+1] != 0);
    g_i64flag = (nz == 0) ? 1 : 0;    // int64 node ids: high words all zero
}

// ---- canonicalize inputs ----
__global__ void k_convx(const void* xp) {    // grid 6250 x 256, x4 vectorized
    int i = (blockIdx.x*256 + threadIdx.x)*4;
    if (g_f32flag) {
        float4 v = *(const float4*)((const float*)xp + i);
        ushort4 o = { f2b(v.x), f2b(v.y), f2b(v.z), f2b(v.w) };
        *(ushort4*)&g_x[i] = o;
    } else {
        *(ushort4*)&g_x[i] = *(const ushort4*)((const u16*)xp + i);
    }
}
struct P18 { const void* p[18]; int off[18]; int n[18]; };
__global__ void k_convpar(P18 a) {
    int f32 = g_f32flag;
    for (int t = 0; t < 18; ++t) {
        const void* s = a.p[t]; int off = a.off[t], n = a.n[t];
        for (int i = blockIdx.x*256 + threadIdx.x; i < n; i += 64*256)
            g_par[off+i] = f32 ? f2b(((const float*)s)[i]) : ((const u16*)s)[i];
    }
}
__global__ void k_init() {   // cursor=1 (self-loop pre-count); must precede k_convidx
    int i = blockIdx.x*256 + threadIdx.x;
    if (i < NN) g_cursor[i] = 1;
}
__global__ void k_convidx(const void* ei, const void* ba) {   // + fused edge count
    int e = blockIdx.x*256 + threadIdx.x;
    int i64 = g_i64flag;
    if (e < NE) {
        int s, d;
        if (i64) { s = (int)((const long long*)ei)[e]; d = (int)((const long long*)ei)[NE + e]; }
        else     { s = ((const int*)ei)[e];            d = ((const int*)ei)[NE + e]; }
        g_src[e] = s; g_dst[e] = d;
        atomicAdd(&g_cursor[d], 1);
    }
    if (e < NN)
        g_batch[e] = i64 ? (int)((const long long*)ba)[e] : ((const int*)ba)[e];
}

// ---- hierarchical exclusive scan of degree counts -> rowptr + scatter cursor ----
__global__ void k_blocksum() {
    int i = blockIdx.x*256 + threadIdx.x;
    int v = (i < NN) ? g_cursor[i] : 0;
    #pragma unroll
    for (int d = 32; d; d >>= 1) v += __shfl_down(v, d);
    __shared__ int lds[4];
    if ((threadIdx.x & 63) == 0) lds[threadIdx.x >> 6] = v;
    __syncthreads();
    if (threadIdx.x == 0) g_bsum[blockIdx.x] = lds[0]+lds[1]+lds[2]+lds[3];
}
__global__ void k_scanb() {     // 1 block x 256 over NB=196 block sums
    __shared__ int lds[4];
    int t = threadIdx.x;
    int v = (t < NB) ? g_bsum[t] : 0;
    int incl = block_incl_scan(v, lds);
    if (t < NB) g_boff[t] = incl - v;     // exclusive
}
__global__ void k_downsweep() {
    __shared__ int lds[4];
    int i = blockIdx.x*256 + threadIdx.x;
    int c = (i < NN) ? g_cursor[i] : 0;
    int incl = block_incl_scan(c, lds);
    int base = g_boff[blockIdx.x];
    if (i < NN) {
        g_rowptr[i+1] = base + incl;
        g_cursor[i]   = base + incl - c;  // exclusive start = scatter cursor
    }
    if (i == 0) g_rowptr[0] = 0;
}
__global__ void k_scatter() {
    int e = blockIdx.x*256 + threadIdx.x;
    if (e >= NET) return;
    int s, d;
    if (e < NE) { s = g_src[e]; d = g_dst[e]; } else { s = d = e - NE; }
    int pos = atomicAdd(&g_cursor[d], 1);
    g_csr[pos] = s;
}

// ---- all 4 weight transposes in one kernel (256 blocks) ----
__global__ void k_transpose4() {
    int which = blockIdx.x >> 6;
    int poff = which==0 ? O_WEMB : which==1 ? O_CW : which==2 ? (O_CW+16384) : O_C2W;
    int idx = (blockIdx.x & 63)*256 + threadIdx.x;
    int n = idx >> 7, k = idx & 127;
    g_WT[which][n*HD + k] = g_par[poff + k*HD + n];
}

// ---- GEMM: out[r][c] = sum_k A[r][k] * W[k][c] ----
__global__ __launch_bounds__(256) void k_gemm(int asel, int wsel, int biasoff,
                                              int outmode, int nrows) {
    __shared__ __align__(16) u16 wt[HD*136];
    const u16* A = asel ? g_hb : g_x;
    const u16* WTg = g_WT[wsel];
    int t = threadIdx.x;
    #pragma unroll
    for (int i = 0; i < 8; ++i) {
        int e = (t + i*256) * 8;
        int n = e >> 7, k = e & 127;
        *(uint4*)&wt[n*136 + k] = *(const uint4*)&WTg[e];
    }
    __syncthreads();
    int lane = t & 63, wave = t >> 6;
    int m16 = lane & 15, q = lane >> 4;
    int row0 = blockIdx.x*128 + wave*32;
    f32x4 acc[2][8];
    #pragma unroll
    for (int a = 0; a < 2; ++a)
        #pragma unroll
        for (int b = 0; b < 8; ++b) acc[a][b] = (f32x4){0.f,0.f,0.f,0.f};
    #pragma unroll
    for (int kc = 0; kc < 4; ++kc) {
        short8 af[2];
        #pragma unroll
        for (int rt = 0; rt < 2; ++rt) {
            int r = row0 + rt*16 + m16; if (r > nrows-1) r = nrows-1;
            af[rt] = *(const short8*)&A[r*HD + kc*32 + q*8];
        }
        #pragma unroll
        for (int ct = 0; ct < 8; ++ct) {
            short8 bf = *(const short8*)&wt[(ct*16 + m16)*136 + kc*32 + q*8];
            acc[0][ct] = __builtin_amdgcn_mfma_f32_16x16x32_bf16(af[0], bf, acc[0][ct], 0,0,0);
            acc[1][ct] = __builtin_amdgcn_mfma_f32_16x16x32_bf16(af[1], bf, acc[1][ct], 0,0,0);
        }
    }
    // C/D layout: col = lane&15, row = q*4 + reg
    #pragma unroll
    for (int rt = 0; rt < 2; ++rt)
        #pragma unroll
        for (int reg = 0; reg < 4; ++reg) {
            int r = row0 + rt*16 + q*4 + reg;
            if (r < nrows) {
                #pragma unroll
                for (int ct = 0; ct < 8; ++ct) {
                    int c = ct*16 + m16;
                    float v = acc[rt][ct][reg];
                    if (biasoff >= 0) v += b2f(g_par[biasoff + c]);
                    if (outmode == 0) { g_h[r*HD+c] = v; g_hb[r*HD+c] = f2b(v); }
                    else              { g_hw[r*HD+c] = f2b(v); }
                }
            }
        }
}

// ---- per-node attention logits (short8-vectorized) ----
__global__ void k_att(int asoff, int adoff, int heads, int ch, int total) {
    int idx = blockIdx.x*256 + threadIdx.x;
    if (idx >= total) return;
    int n = idx / heads, h = idx - n*heads;
    const u16* row = g_hw + n*HD + h*ch;
    const u16* As  = g_par + asoff + h*ch;
    const u16* Ad  = g_par + adoff + h*ch;
    float s1 = 0.f, s2 = 0.f;
    for (int c = 0; c < ch; c += 8) {
        short8 hv = *(const short8*)&row[c];
        short8 sv = *(const short8*)&As[c];
        short8 dv = *(const short8*)&Ad[c];
        #pragma unroll
        for (int k = 0; k < 8; ++k) {
            float w = b2f((u16)hv[k]);
            s1 += w * b2f((u16)sv[k]);
            s2 += w * b2f((u16)dv[k]);
        }
    }
    g_asrc[idx] = s1; g_adst[idx] = s2;
}

// ---- segment softmax + aggregate: one wave per dst node ----
// Logits are bounded (|e| ~ <2; clamped at 30), so plain-exp accumulation is
// exactly the reference softmax up to rounding — no online max needed.
__global__ __launch_bounds__(256) void k_flash(int boff, int heads, int hs) {
    int node = blockIdx.x*4 + (threadIdx.x >> 6);
    int lane = threadIdx.x & 63;
    int c0 = lane*2;
    int head = c0 >> hs;
    float ad = g_adst[node*heads + head];
    int beg = g_rowptr[node], end = g_rowptr[node+1];
    float l = 0.f, o0 = 0.f, o1 = 0.f;
    int s_next = g_csr[beg];               // self-loop guarantees beg < end
    for (int j = beg; j < end; ++j) {
        int s = s_next;
        if (j+1 < end) s_next = g_csr[j+1];        // 1-deep prefetch
        float e = g_asrc[s*heads + head] + ad;
        e = e > 0.f ? e : 0.2f*e;                  // leaky_relu 0.2
        e = fminf(e, 30.f);                        // overflow guard
        float p = __expf(e);
        unsigned w = *(const unsigned*)&g_hw[s*HD + c0];
        l  += p;
        o0 += p*b2f((u16)(w & 0xffff));
        o1 += p*b2f((u16)(w >> 16));
    }
    float inv = 1.f/l;
    g_c[node*HD + c0]     = o0*inv + b2f(g_par[boff + c0]);
    g_c[node*HD + c0 + 1] = o1*inv + b2f(g_par[boff + c0 + 1]);
}

// ---- BatchNorm: per-block partials (no atomics) + small reduce ----
__global__ void k_bnstats() {
    int t = threadIdx.x; int ch = t & 127, r0 = t >> 7;
    int base = blockIdx.x*128;
    float s = 0.f, q = 0.f;
    for (int i = r0; i < 128; i += 2) {
        int n = base + i;
        if (n < NN) { float v = g_c[n*HD + ch]; s += v; q += v*v; }
    }
    __shared__ float sS[256], sQ[256];
    sS[t] = s; sQ[t] = q; __syncthreads();
    if (t < 128) {
        g_bnp1[blockIdx.x*HD + t] = sS[t] + sS[t+128];
        g_bnp2[blockIdx.x*HD + t] = sQ[t] + sQ[t+128];
    }
}
__global__ void k_bnfinal(int goff, int boff) {
    int t = threadIdx.x; if (t >= HD) return;
    float s = 0.f, q = 0.f;
    for (int b = 0; b < NBN; ++b) { s += g_bnp1[b*HD + t]; q += g_bnp2[b*HD + t]; }
    float mean = s / (float)NN;
    float var  = fmaxf(q / (float)NN - mean*mean, 0.f);
    float sc = b2f(g_par[goff + t]) * rsqrtf(var + 1e-5f);
    g_scl[t] = sc;
    g_shf[t] = b2f(g_par[boff + t]) - mean*sc;
}
__global__ void k_bnapply() {   // grid 6250 x 256, x4 vectorized
    int i = (blockIdx.x*256 + threadIdx.x)*4;
    int ch = i & 127;
    float4 c = *(const float4*)&g_c[i];
    float4 h = *(const float4*)&g_h[i];
    float4 r;
    r.x = fmaxf(c.x*g_scl[ch  ] + g_shf[ch  ], 0.f) + h.x;
    r.y = fmaxf(c.y*g_scl[ch+1] + g_shf[ch+1], 0.f) + h.y;
    r.z = fmaxf(c.z*g_scl[ch+2] + g_shf[ch+2], 0.f) + h.z;
    r.w = fmaxf(c.w*g_scl[ch+3] + g_shf[ch+3], 0.f) + h.w;
    *(float4*)&g_h[i] = r;
    ushort4 o = { f2b(r.x), f2b(r.y), f2b(r.z), f2b(r.w) };
    *(ushort4*)&g_hb[i] = o;
}

// ---- graph offsets via binary search over sorted batch ----
__global__ void k_gidx() {    // 1 block x 128
    __shared__ int off[NG+1];
    int g = threadIdx.x;
    if (g <= NG) {
        int lo = 0, hi = NN;
        while (lo < hi) { int mid = (lo+hi) >> 1; if (g_batch[mid] < g) lo = mid+1; else hi = mid; }
        off[g] = lo;
    }
    __syncthreads();
    if (g < NG) { g_goff[g] = off[g]; g_gcnt[g] = off[g+1] - off[g]; }
}

// ---- mean pool, stage 1: 64 graphs x NCH chunks, float4-vectorized ----
// (round-4 profile: 64-block k_pool was 107 us at 2.5% occupancy — grid-starved)
__global__ void k_pool() {
    int g = blockIdx.x / NCH, c = blockIdx.x - g*NCH;
    int cnt = g_gcnt[g], off = g_goff[g];
    int step = (cnt + NCH - 1) / NCH;
    int r0 = c*step, r1 = min(cnt, r0 + step);
    int t = threadIdx.x;
    int ch = (t & 31) * 4;       // float4 channel group
    int rr = t >> 5;             // 8 row-streams per block
    float4 s = {0.f,0.f,0.f,0.f};
    for (int i = r0 + rr; i < r1; i += 8) {
        float4 v = *(const float4*)&g_h[(off + i)*HD + ch];
        s.x += v.x; s.y += v.y; s.z += v.z; s.w += v.w;
    }
    __shared__ float4 sh[256];
    sh[t] = s; __syncthreads();
    if (t < 32) {
        float4 a = sh[t];
        #pragma unroll
        for (int k = 1; k < 8; ++k) {
            float4 b = sh[t + k*32];
            a.x += b.x; a.y += b.y; a.z += b.z; a.w += b.w;
        }
        *(float4*)&g_poolp[(g*NCH + c)*HD + ch] = a;
    }
}
// ---- mean pool, stage 2: reduce chunks, divide by count ----
__global__ void k_poolred() {   // 64 blocks x 128
    int g = blockIdx.x, t = threadIdx.x;
    float s = 0.f;
    for (int c = 0; c < NCH; ++c) s += g_poolp[(g*NCH + c)*HD + t];
    g_pool[g*HD + t] = s / fmaxf((float)g_gcnt[g], 1.f);
}

// ---- tiny dense layers ----
__global__ void k_lin(int insel, int woff, int boff, int outsel, void* outB,
                      int outdim, int dorelu, int total) {
    int idx = blockIdx.x*256 + threadIdx.x;
    if (idx >= total) return;
    const float* in = (insel == 0) ? g_pool : (insel == 1) ? g_t1 : g_t2;
    int g = idx / outdim, j = idx - g*outdim;
    float acc = b2f(g_par[boff + j]);
    const float* ir = in + g*HD;
    for (int k = 0; k < HD; ++k) acc += ir[k] * b2f(g_par[woff + k*outdim + j]);
    if (dorelu && acc < 0.f) acc = 0.f;
    if (outsel == 0)      g_t1[idx] = acc;
    else if (outsel == 1) g_t2[idx] = acc;
    else if (g_f32flag)   ((float*)outB)[idx] = acc;
    else                  ((u16*)outB)[idx] = f2b(acc);
}

extern "C" void kernel_launch(void* const* d_in, const int* in_sizes, int n_in,
                              void* d_out, int out_size, void* d_ws, size_t ws_size,
                              hipStream_t stream) {
    const void* x     = d_in[0];
    const void* ei    = d_in[1];
    const void* batch = d_in[3];

    k_detect<<<1, 64, 0, stream>>>(x, ei);
    k_init<<<NB, 256, 0, stream>>>();
    k_convx<<<6250, 256, 0, stream>>>(x);
    P18 a;
    const int srcidx[18] = {4,5,6,7,8,9,10,11,12,13,14,15,16,17,18,19,20,21};
    const int offs[18] = {O_WEMB,O_BEMB,O_CW,O_CAS,O_CAD,O_CB,O_C2W,O_C2AS,O_C2AD,
                          O_C2B,O_BNG,O_BNB,O_L1W,O_L1B,O_L2W,O_L2B,O_L3W,O_L3B};
    const int lens[18] = {16384,128,32768,256,256,256,16384,128,128,128,384,384,
                          16384,128,16384,128,1280,10};
    for (int t = 0; t < 18; ++t) { a.p[t] = d_in[srcidx[t]]; a.off[t] = offs[t]; a.n[t] = lens[t]; }
    k_convpar<<<64, 256, 0, stream>>>(a);
    k_convidx<<<3125, 256, 0, stream>>>(ei, batch);   // fused edge-count atomics

    k_blocksum<<<NB, 256, 0, stream>>>();
    k_scanb<<<1, 256, 0, stream>>>();
    k_downsweep<<<NB, 256, 0, stream>>>();
    k_scatter<<<3321, 256, 0, stream>>>();
    k_transpose4<<<256, 256, 0, stream>>>();
    k_gidx<<<1, 128, 0, stream>>>();

    // embedding: h = x @ W_emb + b_emb
    k_gemm<<<391, 256, 0, stream>>>(0, 0, O_BEMB, 0, NN);

    for (int L = 0; L < 3; ++L) {
        int heads = (L < 2) ? 8 : 1;
        int ch    = (L < 2) ? 16 : 128;
        int hs    = (L < 2) ? 4 : 7;
        int as    = (L < 2) ? O_CAS + L*128 : O_C2AS;
        int ad    = (L < 2) ? O_CAD + L*128 : O_C2AD;
        int cb    = (L < 2) ? O_CB  + L*128 : O_C2B;
        k_gemm<<<391, 256, 0, stream>>>(1, L+1, -1, 1, NN);
        int atot = NN*heads;
        k_att<<<(atot + 255)/256, 256, 0, stream>>>(as, ad, heads, ch, atot);
        k_flash<<<12500, 256, 0, stream>>>(cb, heads, hs);
        k_bnstats<<<NBN, 256, 0, stream>>>();
        k_bnfinal<<<1, 128, 0, stream>>>(O_BNG + L*HD, O_BNB + L*HD);
        k_bnapply<<<6250, 256, 0, stream>>>();
    }

    k_pool<<<NG*NCH, 256, 0, stream>>>();
    k_poolred<<<NG, 128, 0, stream>>>();
    k_lin<<<32, 256, 0, stream>>>(0, O_L1W, O_L1B, 0, nullptr, HD, 1, NG*HD);
    k_lin<<<32, 256, 0, stream>>>(1, O_L2W, O_L2B, 1, nullptr, HD, 1, NG*HD);
    k_lin<<<3, 256, 0, stream>>>(2, O_L3W, O_L3B, 2, d_out, 10, 0, NG*10);
}

// Round 6
// 671.984 us; speedup vs baseline: 1.8306x; 1.0951x over previous
//
#include <hip/hip_runtime.h>

// GAT_30039001268364: 3-layer GAT + BN + residual + mean-pool + MLP on MI355X.
// Runtime-adaptive input dtypes (f32-vs-bf16, int64-vs-int32 probed on device).

#define NN   50000
#define NE   800000
#define NET  (NE + NN)
#define HD   128
#define NG   64
#define NB   196          // ceil(NN/256)  — 256 items/block kernels
#define NBN  391          // ceil(NN/128)  — 128 nodes/block kernels (BN stats)
#define NCH  20           // pool chunks per graph (64*20 = 1280 blocks)

typedef unsigned short u16;
typedef __attribute__((ext_vector_type(8))) short short8;
typedef __attribute__((ext_vector_type(4))) float f32x4;

// ---- canonical parameter pool offsets (bf16 elements) ----
#define O_WEMB 0
#define O_BEMB 16384
#define O_CW   16512
#define O_CAS  49280
#define O_CAD  49536
#define O_CB   49792
#define O_C2W  50048
#define O_C2AS 66432
#define O_C2AD 66560
#define O_C2B  66688
#define O_BNG  66816
#define O_BNB  67200
#define O_L1W  67584
#define O_L1B  83968
#define O_L2W  84096
#define O_L2B  100480
#define O_L3W  100608
#define O_L3B  101888
#define NPAR   101898

// ---- persistent device scratch ----
__device__ int   g_f32flag, g_i64flag;
__device__ __align__(16) u16 g_x [NN*HD];
__device__ __align__(16) u16 g_par[NPAR];
__device__ int   g_src[NE], g_dst[NE], g_batch[NN];
__device__ __align__(16) float g_h[NN*HD];
__device__ __align__(16) u16 g_hb[NN*HD];
__device__ __align__(16) u16 g_hw[NN*HD];
__device__ __align__(16) float g_c[NN*HD];
__device__ float g_asrc[NN*8];
__device__ float g_adst[NN*8];
__device__ int   g_rowptr[NN+1];
__device__ int   g_cursor[NN];
__device__ int   g_bsum[NB], g_boff[NB];
__device__ int   g_csr[NET];
__device__ float g_bnp1[NBN*HD], g_bnp2[NBN*HD];
__device__ float g_scl[HD], g_shf[HD];
__device__ int   g_gcnt[NG], g_goff[NG];
__device__ __align__(16) float g_poolp[NG*NCH*HD];
__device__ __align__(16) u16 g_WT[4][HD*HD];

__device__ __forceinline__ float b2f(u16 u) {
    unsigned v = ((unsigned)u) << 16; float f; __builtin_memcpy(&f, &v, 4); return f;
}
__device__ __forceinline__ u16 f2b(float f) {
    unsigned v; __builtin_memcpy(&v, &f, 4);
    return (u16)((v + 0x7fffu + ((v >> 16) & 1u)) >> 16);   // RNE
}

// intra-block inclusive scan (256 threads = 4 waves), shuffle-based
__device__ __forceinline__ int block_incl_scan(int v, int* lds4) {
    int t = threadIdx.x, lane = t & 63, w = t >> 6;
    #pragma unroll
    for (int d = 1; d < 64; d <<= 1) {
        int o = __shfl_up(v, d);
        if (lane >= d) v += o;
    }
    if (lane == 63) lds4[w] = v;
    __syncthreads();
    if (w == 0 && lane < 4) {
        int s = lds4[lane];
        #pragma unroll
        for (int d = 1; d < 4; d <<= 1) {
            int o = __shfl_up(s, d);
            if (lane >= d) s += o;
        }
        lds4[lane] = s;
    }
    __syncthreads();
    if (w > 0) v += lds4[w-1];
    return v;
}

// ---- dtype detection ----
__global__ void k_detect(const void* xp, const void* eip) {
    if (threadIdx.x != 0 || blockIdx.x != 0) return;
    const u16* p = (const u16*)xp;
    int f32 = 0;
    for (int i = 0; i < 256; ++i) {
        int ex = (p[i] >> 7) & 0xff;
        if (ex >= 0x93) f32 = 1;      // |v|>=2^20: impossible for bf16 activations
    }
    g_f32flag = f32;
    const int* q = (const int*)eip;
    int nz = 0;
    for (int i = 0; i < 128; ++i) nz += (q[2*i+1] != 0);
    g_i64flag = (nz == 0) ? 1 : 0;    // int64 node ids: high words all zero
}

// ---- canonicalize inputs ----
__global__ void k_convx(const void* xp) {    // grid 6250 x 256, x4 vectorized
    int i = (blockIdx.x*256 + threadIdx.x)*4;
    if (g_f32flag) {
        float4 v = *(const float4*)((const float*)xp + i);
        ushort4 o = { f2b(v.x), f2b(v.y), f2b(v.z), f2b(v.w) };
        *(ushort4*)&g_x[i] = o;
    } else {
        *(ushort4*)&g_x[i] = *(const ushort4*)((const u16*)xp + i);
    }
}
struct P18 { const void* p[18]; int off[18]; int n[18]; };
__global__ void k_convpar(P18 a) {
    int f32 = g_f32flag;
    for (int t = 0; t < 18; ++t) {
        const void* s = a.p[t]; int off = a.off[t], n = a.n[t];
        for (int i = blockIdx.x*256 + threadIdx.x; i < n; i += 64*256)
            g_par[off+i] = f32 ? f2b(((const float*)s)[i]) : ((const u16*)s)[i];
    }
}
__global__ void k_init() {   // cursor=1 (self-loop pre-count); must precede k_convidx
    int i = blockIdx.x*256 + threadIdx.x;
    if (i < NN) g_cursor[i] = 1;
}
__global__ void k_convidx(const void* ei, const void* ba) {   // + fused edge count
    int e = blockIdx.x*256 + threadIdx.x;
    int i64 = g_i64flag;
    if (e < NE) {
        int s, d;
        if (i64) { s = (int)((const long long*)ei)[e]; d = (int)((const long long*)ei)[NE + e]; }
        else     { s = ((const int*)ei)[e];            d = ((const int*)ei)[NE + e]; }
        g_src[e] = s; g_dst[e] = d;
        atomicAdd(&g_cursor[d], 1);
    }
    if (e < NN)
        g_batch[e] = i64 ? (int)((const long long*)ba)[e] : ((const int*)ba)[e];
}

// ---- hierarchical exclusive scan of degree counts -> rowptr + scatter cursor ----
__global__ void k_blocksum() {
    int i = blockIdx.x*256 + threadIdx.x;
    int v = (i < NN) ? g_cursor[i] : 0;
    #pragma unroll
    for (int d = 32; d; d >>= 1) v += __shfl_down(v, d);
    __shared__ int lds[4];
    if ((threadIdx.x & 63) == 0) lds[threadIdx.x >> 6] = v;
    __syncthreads();
    if (threadIdx.x == 0) g_bsum[blockIdx.x] = lds[0]+lds[1]+lds[2]+lds[3];
}
__global__ void k_scanb() {     // 1 block x 256 over NB=196 block sums
    __shared__ int lds[4];
    int t = threadIdx.x;
    int v = (t < NB) ? g_bsum[t] : 0;
    int incl = block_incl_scan(v, lds);
    if (t < NB) g_boff[t] = incl - v;     // exclusive
}
__global__ void k_downsweep() {
    __shared__ int lds[4];
    int i = blockIdx.x*256 + threadIdx.x;
    int c = (i < NN) ? g_cursor[i] : 0;
    int incl = block_incl_scan(c, lds);
    int base = g_boff[blockIdx.x];
    if (i < NN) {
        g_rowptr[i+1] = base + incl;
        g_cursor[i]   = base + incl - c;  // exclusive start = scatter cursor
    }
    if (i == 0) g_rowptr[0] = 0;
}
__global__ void k_scatter() {
    int e = blockIdx.x*256 + threadIdx.x;
    if (e >= NET) return;
    int s, d;
    if (e < NE) { s = g_src[e]; d = g_dst[e]; } else { s = d = e - NE; }
    int pos = atomicAdd(&g_cursor[d], 1);
    g_csr[pos] = s;
}

// ---- all 4 weight transposes in one kernel (256 blocks) ----
__global__ void k_transpose4() {
    int which = blockIdx.x >> 6;
    int poff = which==0 ? O_WEMB : which==1 ? O_CW : which==2 ? (O_CW+16384) : O_C2W;
    int idx = (blockIdx.x & 63)*256 + threadIdx.x;
    int n = idx >> 7, k = idx & 127;
    g_WT[which][n*HD + k] = g_par[poff + k*HD + n];
}

// ---- GEMM: out[r][c] = sum_k A[r][k] * W[k][c] ----
__global__ __launch_bounds__(256) void k_gemm(int asel, int wsel, int biasoff,
                                              int outmode, int nrows) {
    __shared__ __align__(16) u16 wt[HD*136];
    const u16* A = asel ? g_hb : g_x;
    const u16* WTg = g_WT[wsel];
    int t = threadIdx.x;
    #pragma unroll
    for (int i = 0; i < 8; ++i) {
        int e = (t + i*256) * 8;
        int n = e >> 7, k = e & 127;
        *(uint4*)&wt[n*136 + k] = *(const uint4*)&WTg[e];
    }
    __syncthreads();
    int lane = t & 63, wave = t >> 6;
    int m16 = lane & 15, q = lane >> 4;
    int row0 = blockIdx.x*128 + wave*32;
    f32x4 acc[2][8];
    #pragma unroll
    for (int a = 0; a < 2; ++a)
        #pragma unroll
        for (int b = 0; b < 8; ++b) acc[a][b] = (f32x4){0.f,0.f,0.f,0.f};
    #pragma unroll
    for (int kc = 0; kc < 4; ++kc) {
        short8 af[2];
        #pragma unroll
        for (int rt = 0; rt < 2; ++rt) {
            int r = row0 + rt*16 + m16; if (r > nrows-1) r = nrows-1;
            af[rt] = *(const short8*)&A[r*HD + kc*32 + q*8];
        }
        #pragma unroll
        for (int ct = 0; ct < 8; ++ct) {
            short8 bf = *(const short8*)&wt[(ct*16 + m16)*136 + kc*32 + q*8];
            acc[0][ct] = __builtin_amdgcn_mfma_f32_16x16x32_bf16(af[0], bf, acc[0][ct], 0,0,0);
            acc[1][ct] = __builtin_amdgcn_mfma_f32_16x16x32_bf16(af[1], bf, acc[1][ct], 0,0,0);
        }
    }
    // C/D layout: col = lane&15, row = q*4 + reg
    #pragma unroll
    for (int rt = 0; rt < 2; ++rt)
        #pragma unroll
        for (int reg = 0; reg < 4; ++reg) {
            int r = row0 + rt*16 + q*4 + reg;
            if (r < nrows) {
                #pragma unroll
                for (int ct = 0; ct < 8; ++ct) {
                    int c = ct*16 + m16;
                    float v = acc[rt][ct][reg];
                    if (biasoff >= 0) v += b2f(g_par[biasoff + c]);
                    if (outmode == 0) { g_h[r*HD+c] = v; g_hb[r*HD+c] = f2b(v); }
                    else              { g_hw[r*HD+c] = f2b(v); }
                }
            }
        }
}

// ---- per-node attention logits (short8-vectorized) ----
__global__ void k_att(int asoff, int adoff, int heads, int ch, int total) {
    int idx = blockIdx.x*256 + threadIdx.x;
    if (idx >= total) return;
    int n = idx / heads, h = idx - n*heads;
    const u16* row = g_hw + n*HD + h*ch;
    const u16* As  = g_par + asoff + h*ch;
    const u16* Ad  = g_par + adoff + h*ch;
    float s1 = 0.f, s2 = 0.f;
    for (int c = 0; c < ch; c += 8) {
        short8 hv = *(const short8*)&row[c];
        short8 sv = *(const short8*)&As[c];
        short8 dv = *(const short8*)&Ad[c];
        #pragma unroll
        for (int k = 0; k < 8; ++k) {
            float w = b2f((u16)hv[k]);
            s1 += w * b2f((u16)sv[k]);
            s2 += w * b2f((u16)dv[k]);
        }
    }
    g_asrc[idx] = s1; g_adst[idx] = s2;
}

// ---- segment softmax + aggregate: one wave per dst node, 4-wide edge batching.
// Round-5 profile: 1-edge/iter chain was latency-bound (VALU 48%, HBM 32%).
// Batching 4 edges issues 4 csr + 4 asrc + 4 row gathers before any consume.
// Logits bounded (clamp 30) => plain-exp == reference softmax up to rounding.
__global__ __launch_bounds__(256) void k_flash(int boff, int heads, int hs) {
    int node = blockIdx.x*4 + (threadIdx.x >> 6);
    int lane = threadIdx.x & 63;
    int c0 = lane*2;
    int head = c0 >> hs;
    float ad = g_adst[node*heads + head];
    int beg = g_rowptr[node], end = g_rowptr[node+1];
    float l = 0.f, o0 = 0.f, o1 = 0.f;
    int j = beg;
    for (; j + 4 <= end; j += 4) {
        int s0 = g_csr[j], s1 = g_csr[j+1], s2 = g_csr[j+2], s3 = g_csr[j+3];
        float a0 = g_asrc[s0*heads + head];
        float a1 = g_asrc[s1*heads + head];
        float a2 = g_asrc[s2*heads + head];
        float a3 = g_asrc[s3*heads + head];
        unsigned w0 = *(const unsigned*)&g_hw[s0*HD + c0];
        unsigned w1 = *(const unsigned*)&g_hw[s1*HD + c0];
        unsigned w2 = *(const unsigned*)&g_hw[s2*HD + c0];
        unsigned w3 = *(const unsigned*)&g_hw[s3*HD + c0];
        float e0 = a0 + ad; e0 = fmaxf(e0, 0.2f*e0);
        float e1 = a1 + ad; e1 = fmaxf(e1, 0.2f*e1);
        float e2 = a2 + ad; e2 = fmaxf(e2, 0.2f*e2);
        float e3 = a3 + ad; e3 = fmaxf(e3, 0.2f*e3);
        float p0 = __expf(fminf(e0, 30.f));
        float p1 = __expf(fminf(e1, 30.f));
        float p2 = __expf(fminf(e2, 30.f));
        float p3 = __expf(fminf(e3, 30.f));
        l += (p0 + p1) + (p2 + p3);
        o0 += p0*b2f((u16)(w0 & 0xffff));
        o1 += p0*b2f((u16)(w0 >> 16));
        o0 += p1*b2f((u16)(w1 & 0xffff));
        o1 += p1*b2f((u16)(w1 >> 16));
        o0 += p2*b2f((u16)(w2 & 0xffff));
        o1 += p2*b2f((u16)(w2 >> 16));
        o0 += p3*b2f((u16)(w3 & 0xffff));
        o1 += p3*b2f((u16)(w3 >> 16));
    }
    for (; j < end; ++j) {
        int s = g_csr[j];
        float e = g_asrc[s*heads + head] + ad;
        e = fmaxf(e, 0.2f*e);
        float p = __expf(fminf(e, 30.f));
        unsigned w = *(const unsigned*)&g_hw[s*HD + c0];
        l  += p;
        o0 += p*b2f((u16)(w & 0xffff));
        o1 += p*b2f((u16)(w >> 16));
    }
    float inv = 1.f/l;                       // l>0: self-loop guarantees >=1 edge
    g_c[node*HD + c0]     = o0*inv + b2f(g_par[boff + c0]);
    g_c[node*HD + c0 + 1] = o1*inv + b2f(g_par[boff + c0 + 1]);
}

// ---- BatchNorm: per-block partials (no atomics) + small reduce ----
__global__ void k_bnstats() {
    int t = threadIdx.x; int ch = t & 127, r0 = t >> 7;
    int base = blockIdx.x*128;
    float s = 0.f, q = 0.f;
    for (int i = r0; i < 128; i += 2) {
        int n = base + i;
        if (n < NN) { float v = g_c[n*HD + ch]; s += v; q += v*v; }
    }
    __shared__ float sS[256], sQ[256];
    sS[t] = s; sQ[t] = q; __syncthreads();
    if (t < 128) {
        g_bnp1[blockIdx.x*HD + t] = sS[t] + sS[t+128];
        g_bnp2[blockIdx.x*HD + t] = sQ[t] + sQ[t+128];
    }
}
__global__ void k_bnfinal(int goff, int boff) {
    int t = threadIdx.x; if (t >= HD) return;
    float s = 0.f, q = 0.f;
    for (int b = 0; b < NBN; ++b) { s += g_bnp1[b*HD + t]; q += g_bnp2[b*HD + t]; }
    float mean = s / (float)NN;
    float var  = fmaxf(q / (float)NN - mean*mean, 0.f);
    float sc = b2f(g_par[goff + t]) * rsqrtf(var + 1e-5f);
    g_scl[t] = sc;
    g_shf[t] = b2f(g_par[boff + t]) - mean*sc;
}
__global__ void k_bnapply() {   // grid 6250 x 256, x4 vectorized
    int i = (blockIdx.x*256 + threadIdx.x)*4;
    int ch = i & 127;
    float4 c = *(const float4*)&g_c[i];
    float4 h = *(const float4*)&g_h[i];
    float4 r;
    r.x = fmaxf(c.x*g_scl[ch  ] + g_shf[ch  ], 0.f) + h.x;
    r.y = fmaxf(c.y*g_scl[ch+1] + g_shf[ch+1], 0.f) + h.y;
    r.z = fmaxf(c.z*g_scl[ch+2] + g_shf[ch+2], 0.f) + h.z;
    r.w = fmaxf(c.w*g_scl[ch+3] + g_shf[ch+3], 0.f) + h.w;
    *(float4*)&g_h[i] = r;
    ushort4 o = { f2b(r.x), f2b(r.y), f2b(r.z), f2b(r.w) };
    *(ushort4*)&g_hb[i] = o;
}

// ---- graph offsets via binary search over sorted batch ----
__global__ void k_gidx() {    // 1 block x 128
    __shared__ int off[NG+1];
    int g = threadIdx.x;
    if (g <= NG) {
        int lo = 0, hi = NN;
        while (lo < hi) { int mid = (lo+hi) >> 1; if (g_batch[mid] < g) lo = mid+1; else hi = mid; }
        off[g] = lo;
    }
    __syncthreads();
    if (g < NG) { g_goff[g] = off[g]; g_gcnt[g] = off[g+1] - off[g]; }
}

// ---- mean pool, stage 1: 64 graphs x NCH chunks, float4-vectorized ----
__global__ void k_pool() {
    int g = blockIdx.x / NCH, c = blockIdx.x - g*NCH;
    int cnt = g_gcnt[g], off = g_goff[g];
    int step = (cnt + NCH - 1) / NCH;
    int r0 = c*step, r1 = min(cnt, r0 + step);
    int t = threadIdx.x;
    int ch = (t & 31) * 4;       // float4 channel group
    int rr = t >> 5;             // 8 row-streams per block
    float4 s = {0.f,0.f,0.f,0.f};
    for (int i = r0 + rr; i < r1; i += 8) {
        float4 v = *(const float4*)&g_h[(off + i)*HD + ch];
        s.x += v.x; s.y += v.y; s.z += v.z; s.w += v.w;
    }
    __shared__ float4 sh[256];
    sh[t] = s; __syncthreads();
    if (t < 32) {
        float4 a = sh[t];
        #pragma unroll
        for (int k = 1; k < 8; ++k) {
            float4 b = sh[t + k*32];
            a.x += b.x; a.y += b.y; a.z += b.z; a.w += b.w;
        }
        *(float4*)&g_poolp[(g*NCH + c)*HD + ch] = a;
    }
}

// ---- fused head: pool-reduce + lin1 + lin2 + lin3, one block per graph ----
__global__ void k_head(void* outB) {
    __shared__ float pl[HD], h1[HD], h2[HD];
    int g = blockIdx.x, t = threadIdx.x;   // 128 threads
    float s = 0.f;
    for (int c = 0; c < NCH; ++c) s += g_poolp[(g*NCH + c)*HD + t];
    pl[t] = s / fmaxf((float)g_gcnt[g], 1.f);
    __syncthreads();
    float acc = b2f(g_par[O_L1B + t]);
    for (int k = 0; k < HD; ++k) acc += pl[k] * b2f(g_par[O_L1W + k*HD + t]);
    h1[t] = fmaxf(acc, 0.f);
    __syncthreads();
    acc = b2f(g_par[O_L2B + t]);
    for (int k = 0; k < HD; ++k) acc += h1[k] * b2f(g_par[O_L2W + k*HD + t]);
    h2[t] = fmaxf(acc, 0.f);
    __syncthreads();
    if (t < 10) {
        acc = b2f(g_par[O_L3B + t]);
        for (int k = 0; k < HD; ++k) acc += h2[k] * b2f(g_par[O_L3W + k*10 + t]);
        if (g_f32flag) ((float*)outB)[g*10 + t] = acc;
        else           ((u16*)outB)[g*10 + t] = f2b(acc);
    }
}

extern "C" void kernel_launch(void* const* d_in, const int* in_sizes, int n_in,
                              void* d_out, int out_size, void* d_ws, size_t ws_size,
                              hipStream_t stream) {
    const void* x     = d_in[0];
    const void* ei    = d_in[1];
    const void* batch = d_in[3];

    k_detect<<<1, 64, 0, stream>>>(x, ei);
    k_init<<<NB, 256, 0, stream>>>();
    k_convx<<<6250, 256, 0, stream>>>(x);
    P18 a;
    const int srcidx[18] = {4,5,6,7,8,9,10,11,12,13,14,15,16,17,18,19,20,21};
    const int offs[18] = {O_WEMB,O_BEMB,O_CW,O_CAS,O_CAD,O_CB,O_C2W,O_C2AS,O_C2AD,
                          O_C2B,O_BNG,O_BNB,O_L1W,O_L1B,O_L2W,O_L2B,O_L3W,O_L3B};
    const int lens[18] = {16384,128,32768,256,256,256,16384,128,128,128,384,384,
                          16384,128,16384,128,1280,10};
    for (int t = 0; t < 18; ++t) { a.p[t] = d_in[srcidx[t]]; a.off[t] = offs[t]; a.n[t] = lens[t]; }
    k_convpar<<<64, 256, 0, stream>>>(a);
    k_convidx<<<3125, 256, 0, stream>>>(ei, batch);   // fused edge-count atomics

    k_blocksum<<<NB, 256, 0, stream>>>();
    k_scanb<<<1, 256, 0, stream>>>();
    k_downsweep<<<NB, 256, 0, stream>>>();
    k_scatter<<<3321, 256, 0, stream>>>();
    k_transpose4<<<256, 256, 0, stream>>>();
    k_gidx<<<1, 128, 0, stream>>>();

    // embedding: h = x @ W_emb + b_emb
    k_gemm<<<391, 256, 0, stream>>>(0, 0, O_BEMB, 0, NN);

    for (int L = 0; L < 3; ++L) {
        int heads = (L < 2) ? 8 : 1;
        int ch    = (L < 2) ? 16 : 128;
        int hs    = (L < 2) ? 4 : 7;
        int as    = (L < 2) ? O_CAS + L*128 : O_C2AS;
        int ad    = (L < 2) ? O_CAD + L*128 : O_C2AD;
        int cb    = (L < 2) ? O_CB  + L*128 : O_C2B;
        k_gemm<<<391, 256, 0, stream>>>(1, L+1, -1, 1, NN);
        int atot = NN*heads;
        k_att<<<(atot + 255)/256, 256, 0, stream>>>(as, ad, heads, ch, atot);
        k_flash<<<12500, 256, 0, stream>>>(cb, heads, hs);
        k_bnstats<<<NBN, 256, 0, stream>>>();
        k_bnfinal<<<1, 128, 0, stream>>>(O_BNG + L*HD, O_BNB + L*HD);
        k_bnapply<<<6250, 256, 0, stream>>>();
    }

    k_pool<<<NG*NCH, 256, 0, stream>>>();
    k_head<<<NG, 128, 0, stream>>>(d_out);
}

// Round 7
// 646.352 us; speedup vs baseline: 1.9032x; 1.0397x over previous
//
#include <hip/hip_runtime.h>

// GAT_30039001268364: 3-layer GAT + BN + residual + mean-pool + MLP on MI355X.
// Runtime-adaptive input dtypes (f32-vs-bf16, int64-vs-int32 probed on device).

#define NN   50000
#define NE   800000
#define NET  (NE + NN)
#define HD   128
#define NG   64
#define NB   196          // ceil(NN/256)  — 256 items/block kernels
#define NBN  391          // ceil(NN/128)  — 128 nodes/block kernels (BN stats)
#define NCH  20           // pool chunks per graph (64*20 = 1280 blocks)
#define NTILE 3321        // ceil(NET/256) — edge tiles
#define PSZ  6250         // dst-partition size (8 partitions cover 50000)

typedef unsigned short u16;
typedef __attribute__((ext_vector_type(8))) short short8;
typedef __attribute__((ext_vector_type(4))) float f32x4;

// ---- canonical parameter pool offsets (bf16 elements) ----
#define O_WEMB 0
#define O_BEMB 16384
#define O_CW   16512
#define O_CAS  49280
#define O_CAD  49536
#define O_CB   49792
#define O_C2W  50048
#define O_C2AS 66432
#define O_C2AD 66560
#define O_C2B  66688
#define O_BNG  66816
#define O_BNB  67200
#define O_L1W  67584
#define O_L1B  83968
#define O_L2W  84096
#define O_L2B  100480
#define O_L3W  100608
#define O_L3B  101888
#define NPAR   101898

// ---- persistent device scratch ----
__device__ int   g_f32flag, g_i64flag;
__device__ __align__(16) u16 g_x [NN*HD];
__device__ __align__(16) u16 g_par[NPAR];
__device__ int   g_src[NE], g_dst[NE], g_batch[NN];
__device__ __align__(16) float g_h[NN*HD];
__device__ __align__(16) u16 g_hb[NN*HD];
__device__ __align__(16) u16 g_hw[NN*HD];
__device__ __align__(16) float g_c[NN*HD];
__device__ float g_asrc[NN*8];
__device__ float g_adst[NN*8];
__device__ int   g_rowptr[NN+1];
__device__ int   g_cursor[NN];
__device__ int   g_bsum[NB], g_boff[NB];
__device__ int   g_csr[NET];
__device__ float g_bnp1[NBN*HD], g_bnp2[NBN*HD];
__device__ float g_scl[HD], g_shf[HD];
__device__ int   g_gcnt[NG], g_goff[NG];
__device__ __align__(16) float g_poolp[NG*NCH*HD];
__device__ __align__(16) u16 g_WT[4][HD*HD];

__device__ __forceinline__ float b2f(u16 u) {
    unsigned v = ((unsigned)u) << 16; float f; __builtin_memcpy(&f, &v, 4); return f;
}
__device__ __forceinline__ u16 f2b(float f) {
    unsigned v; __builtin_memcpy(&v, &f, 4);
    return (u16)((v + 0x7fffu + ((v >> 16) & 1u)) >> 16);   // RNE
}

// intra-block inclusive scan (256 threads = 4 waves), shuffle-based
__device__ __forceinline__ int block_incl_scan(int v, int* lds4) {
    int t = threadIdx.x, lane = t & 63, w = t >> 6;
    #pragma unroll
    for (int d = 1; d < 64; d <<= 1) {
        int o = __shfl_up(v, d);
        if (lane >= d) v += o;
    }
    if (lane == 63) lds4[w] = v;
    __syncthreads();
    if (w == 0 && lane < 4) {
        int s = lds4[lane];
        #pragma unroll
        for (int d = 1; d < 4; d <<= 1) {
            int o = __shfl_up(s, d);
            if (lane >= d) s += o;
        }
        lds4[lane] = s;
    }
    __syncthreads();
    if (w > 0) v += lds4[w-1];
    return v;
}

// ---- dtype detection ----
__global__ void k_detect(const void* xp, const void* eip) {
    if (threadIdx.x != 0 || blockIdx.x != 0) return;
    const u16* p = (const u16*)xp;
    int f32 = 0;
    for (int i = 0; i < 256; ++i) {
        int ex = (p[i] >> 7) & 0xff;
        if (ex >= 0x93) f32 = 1;      // |v|>=2^20: impossible for bf16 activations
    }
    g_f32flag = f32;
    const int* q = (const int*)eip;
    int nz = 0;
    for (int i = 0; i < 128; ++i) nz += (q[2*i+1] != 0);
    g_i64flag = (nz == 0) ? 1 : 0;    // int64 node ids: high words all zero
}

// ---- canonicalize inputs ----
__global__ void k_convx(const void* xp) {    // grid 6250 x 256, x4 vectorized
    int i = (blockIdx.x*256 + threadIdx.x)*4;
    if (g_f32flag) {
        float4 v = *(const float4*)((const float*)xp + i);
        ushort4 o = { f2b(v.x), f2b(v.y), f2b(v.z), f2b(v.w) };
        *(ushort4*)&g_x[i] = o;
    } else {
        *(ushort4*)&g_x[i] = *(const ushort4*)((const u16*)xp + i);
    }
}
struct P18 { const void* p[18]; int off[18]; int n[18]; };
__global__ void k_convpar(P18 a) {
    int f32 = g_f32flag;
    for (int t = 0; t < 18; ++t) {
        const void* s = a.p[t]; int off = a.off[t], n = a.n[t];
        for (int i = blockIdx.x*256 + threadIdx.x; i < n; i += 64*256)
            g_par[off+i] = f32 ? f2b(((const float*)s)[i]) : ((const u16*)s)[i];
    }
}
__global__ void k_init() {   // cursor=1 (self-loop pre-count); must precede k_convidx
    int i = blockIdx.x*256 + threadIdx.x;
    if (i < NN) g_cursor[i] = 1;
}
__global__ void k_convidx(const void* ei, const void* ba) {   // + fused edge count
    int e = blockIdx.x*256 + threadIdx.x;
    int i64 = g_i64flag;
    if (e < NE) {
        int s, d;
        if (i64) { s = (int)((const long long*)ei)[e]; d = (int)((const long long*)ei)[NE + e]; }
        else     { s = ((const int*)ei)[e];            d = ((const int*)ei)[NE + e]; }
        g_src[e] = s; g_dst[e] = d;
        atomicAdd(&g_cursor[d], 1);
    }
    if (e < NN)
        g_batch[e] = i64 ? (int)((const long long*)ba)[e] : ((const int*)ba)[e];
}

// ---- hierarchical exclusive scan of degree counts -> rowptr + scatter cursor ----
__global__ void k_blocksum() {
    int i = blockIdx.x*256 + threadIdx.x;
    int v = (i < NN) ? g_cursor[i] : 0;
    #pragma unroll
    for (int d = 32; d; d >>= 1) v += __shfl_down(v, d);
    __shared__ int lds[4];
    if ((threadIdx.x & 63) == 0) lds[threadIdx.x >> 6] = v;
    __syncthreads();
    if (threadIdx.x == 0) g_bsum[blockIdx.x] = lds[0]+lds[1]+lds[2]+lds[3];
}
__global__ void k_scanb() {     // 1 block x 256 over NB=196 block sums
    __shared__ int lds[4];
    int t = threadIdx.x;
    int v = (t < NB) ? g_bsum[t] : 0;
    int incl = block_incl_scan(v, lds);
    if (t < NB) g_boff[t] = incl - v;     // exclusive
}
__global__ void k_downsweep() {
    __shared__ int lds[4];
    int i = blockIdx.x*256 + threadIdx.x;
    int c = (i < NN) ? g_cursor[i] : 0;
    int incl = block_incl_scan(c, lds);
    int base = g_boff[blockIdx.x];
    if (i < NN) {
        g_rowptr[i+1] = base + incl;
        g_cursor[i]   = base + incl - c;  // exclusive start = scatter cursor
    }
    if (i == 0) g_rowptr[0] = 0;
}

// ---- scatter, XCD-affine dst partitioning ----
// Round-6 profile: flat scatter had WRITE_SIZE 55 MB for 3.4 MB of payload —
// 64B-line writebacks from 8 non-coherent L2s, one per store. Partitioning dst
// into 8 ranges handled by blockIdx&7 (round-robin XCD mapping) keeps each
// 425 KB g_csr range dirty in a single L2 until eviction.
__global__ void k_scatter() {   // grid NTILE*8
    int part = blockIdx.x & 7;
    int e = (blockIdx.x >> 3)*256 + threadIdx.x;
    if (e >= NET) return;
    int s, d;
    if (e < NE) { s = g_src[e]; d = g_dst[e]; } else { s = d = e - NE; }
    if (d / PSZ != part) return;
    int pos = atomicAdd(&g_cursor[d], 1);
    g_csr[pos] = s;
}

// ---- all 4 weight transposes in one kernel (256 blocks) ----
__global__ void k_transpose4() {
    int which = blockIdx.x >> 6;
    int poff = which==0 ? O_WEMB : which==1 ? O_CW : which==2 ? (O_CW+16384) : O_C2W;
    int idx = (blockIdx.x & 63)*256 + threadIdx.x;
    int n = idx >> 7, k = idx & 127;
    g_WT[which][n*HD + k] = g_par[poff + k*HD + n];
}

// ---- GEMM: out[r][c] = sum_k A[r][k] * W[k][c] ----
__global__ __launch_bounds__(256) void k_gemm(int asel, int wsel, int biasoff,
                                              int outmode, int nrows) {
    __shared__ __align__(16) u16 wt[HD*136];
    const u16* A = asel ? g_hb : g_x;
    const u16* WTg = g_WT[wsel];
    int t = threadIdx.x;
    #pragma unroll
    for (int i = 0; i < 8; ++i) {
        int e = (t + i*256) * 8;
        int n = e >> 7, k = e & 127;
        *(uint4*)&wt[n*136 + k] = *(const uint4*)&WTg[e];
    }
    __syncthreads();
    int lane = t & 63, wave = t >> 6;
    int m16 = lane & 15, q = lane >> 4;
    int row0 = blockIdx.x*128 + wave*32;
    f32x4 acc[2][8];
    #pragma unroll
    for (int a = 0; a < 2; ++a)
        #pragma unroll
        for (int b = 0; b < 8; ++b) acc[a][b] = (f32x4){0.f,0.f,0.f,0.f};
    #pragma unroll
    for (int kc = 0; kc < 4; ++kc) {
        short8 af[2];
        #pragma unroll
        for (int rt = 0; rt < 2; ++rt) {
            int r = row0 + rt*16 + m16; if (r > nrows-1) r = nrows-1;
            af[rt] = *(const short8*)&A[r*HD + kc*32 + q*8];
        }
        #pragma unroll
        for (int ct = 0; ct < 8; ++ct) {
            short8 bf = *(const short8*)&wt[(ct*16 + m16)*136 + kc*32 + q*8];
            acc[0][ct] = __builtin_amdgcn_mfma_f32_16x16x32_bf16(af[0], bf, acc[0][ct], 0,0,0);
            acc[1][ct] = __builtin_amdgcn_mfma_f32_16x16x32_bf16(af[1], bf, acc[1][ct], 0,0,0);
        }
    }
    // C/D layout: col = lane&15, row = q*4 + reg
    #pragma unroll
    for (int rt = 0; rt < 2; ++rt)
        #pragma unroll
        for (int reg = 0; reg < 4; ++reg) {
            int r = row0 + rt*16 + q*4 + reg;
            if (r < nrows) {
                #pragma unroll
                for (int ct = 0; ct < 8; ++ct) {
                    int c = ct*16 + m16;
                    float v = acc[rt][ct][reg];
                    if (biasoff >= 0) v += b2f(g_par[biasoff + c]);
                    if (outmode == 0) { g_h[r*HD+c] = v; g_hb[r*HD+c] = f2b(v); }
                    else              { g_hw[r*HD+c] = f2b(v); }
                }
            }
        }
}

// ---- per-node attention logits (short8-vectorized) ----
__global__ void k_att(int asoff, int adoff, int heads, int ch, int total) {
    int idx = blockIdx.x*256 + threadIdx.x;
    if (idx >= total) return;
    int n = idx / heads, h = idx - n*heads;
    const u16* row = g_hw + n*HD + h*ch;
    const u16* As  = g_par + asoff + h*ch;
    const u16* Ad  = g_par + adoff + h*ch;
    float s1 = 0.f, s2 = 0.f;
    for (int c = 0; c < ch; c += 8) {
        short8 hv = *(const short8*)&row[c];
        short8 sv = *(const short8*)&As[c];
        short8 dv = *(const short8*)&Ad[c];
        #pragma unroll
        for (int k = 0; k < 8; ++k) {
            float w = b2f((u16)hv[k]);
            s1 += w * b2f((u16)sv[k]);
            s2 += w * b2f((u16)dv[k]);
        }
    }
    g_asrc[idx] = s1; g_adst[idx] = s2;
}

// ---- segment softmax + aggregate: one wave per dst node, 8/4/1 edge batching.
// Wave's 64 lanes read one 256B g_hw row per edge (coalesced); batching keeps
// up to 24 loads in flight. Logits bounded (clamp 30) => plain exp == reference
// softmax up to rounding.
__global__ __launch_bounds__(256) void k_flash(int boff, int heads, int hs) {
    int node = blockIdx.x*4 + (threadIdx.x >> 6);
    int lane = threadIdx.x & 63;
    int c0 = lane*2;
    int head = c0 >> hs;
    float ad = g_adst[node*heads + head];
    int beg = g_rowptr[node], end = g_rowptr[node+1];
    float l = 0.f, o0 = 0.f, o1 = 0.f;
    int j = beg;
    for (; j + 8 <= end; j += 8) {
        int s[8]; float av[8]; unsigned w[8];
        #pragma unroll
        for (int k = 0; k < 8; ++k) s[k] = g_csr[j+k];
        #pragma unroll
        for (int k = 0; k < 8; ++k) av[k] = g_asrc[s[k]*heads + head];
        #pragma unroll
        for (int k = 0; k < 8; ++k) w[k] = *(const unsigned*)&g_hw[s[k]*HD + c0];
        #pragma unroll
        for (int k = 0; k < 8; ++k) {
            float e = av[k] + ad;
            e = fmaxf(e, 0.2f*e);
            float p = __expf(fminf(e, 30.f));
            l  += p;
            o0 += p*b2f((u16)(w[k] & 0xffff));
            o1 += p*b2f((u16)(w[k] >> 16));
        }
    }
    for (; j + 4 <= end; j += 4) {
        int s[4]; float av[4]; unsigned w[4];
        #pragma unroll
        for (int k = 0; k < 4; ++k) s[k] = g_csr[j+k];
        #pragma unroll
        for (int k = 0; k < 4; ++k) av[k] = g_asrc[s[k]*heads + head];
        #pragma unroll
        for (int k = 0; k < 4; ++k) w[k] = *(const unsigned*)&g_hw[s[k]*HD + c0];
        #pragma unroll
        for (int k = 0; k < 4; ++k) {
            float e = av[k] + ad;
            e = fmaxf(e, 0.2f*e);
            float p = __expf(fminf(e, 30.f));
            l  += p;
            o0 += p*b2f((u16)(w[k] & 0xffff));
            o1 += p*b2f((u16)(w[k] >> 16));
        }
    }
    for (; j < end; ++j) {
        int s = g_csr[j];
        float e = g_asrc[s*heads + head] + ad;
        e = fmaxf(e, 0.2f*e);
        float p = __expf(fminf(e, 30.f));
        unsigned w = *(const unsigned*)&g_hw[s*HD + c0];
        l  += p;
        o0 += p*b2f((u16)(w & 0xffff));
        o1 += p*b2f((u16)(w >> 16));
    }
    float inv = 1.f/l;                       // l>0: self-loop guarantees >=1 edge
    g_c[node*HD + c0]     = o0*inv + b2f(g_par[boff + c0]);
    g_c[node*HD + c0 + 1] = o1*inv + b2f(g_par[boff + c0 + 1]);
}

// ---- BatchNorm: per-block partials (no atomics) + small reduce ----
__global__ void k_bnstats() {
    int t = threadIdx.x; int ch = t & 127, r0 = t >> 7;
    int base = blockIdx.x*128;
    float s = 0.f, q = 0.f;
    for (int i = r0; i < 128; i += 2) {
        int n = base + i;
        if (n < NN) { float v = g_c[n*HD + ch]; s += v; q += v*v; }
    }
    __shared__ float sS[256], sQ[256];
    sS[t] = s; sQ[t] = q; __syncthreads();
    if (t < 128) {
        g_bnp1[blockIdx.x*HD + t] = sS[t] + sS[t+128];
        g_bnp2[blockIdx.x*HD + t] = sQ[t] + sQ[t+128];
    }
}
__global__ void k_bnfinal(int goff, int boff) {
    int t = threadIdx.x; if (t >= HD) return;
    float s = 0.f, q = 0.f;
    for (int b = 0; b < NBN; ++b) { s += g_bnp1[b*HD + t]; q += g_bnp2[b*HD + t]; }
    float mean = s / (float)NN;
    float var  = fmaxf(q / (float)NN - mean*mean, 0.f);
    float sc = b2f(g_par[goff + t]) * rsqrtf(var + 1e-5f);
    g_scl[t] = sc;
    g_shf[t] = b2f(g_par[boff + t]) - mean*sc;
}
__global__ void k_bnapply() {   // grid 6250 x 256, x4 vectorized
    int i = (blockIdx.x*256 + threadIdx.x)*4;
    int ch = i & 127;
    float4 c = *(const float4*)&g_c[i];
    float4 h = *(const float4*)&g_h[i];
    float4 r;
    r.x = fmaxf(c.x*g_scl[ch  ] + g_shf[ch  ], 0.f) + h.x;
    r.y = fmaxf(c.y*g_scl[ch+1] + g_shf[ch+1], 0.f) + h.y;
    r.z = fmaxf(c.z*g_scl[ch+2] + g_shf[ch+2], 0.f) + h.z;
    r.w = fmaxf(c.w*g_scl[ch+3] + g_shf[ch+3], 0.f) + h.w;
    *(float4*)&g_h[i] = r;
    ushort4 o = { f2b(r.x), f2b(r.y), f2b(r.z), f2b(r.w) };
    *(ushort4*)&g_hb[i] = o;
}

// ---- graph offsets via binary search over sorted batch ----
__global__ void k_gidx() {    // 1 block x 128
    __shared__ int off[NG+1];
    int g = threadIdx.x;
    if (g <= NG) {
        int lo = 0, hi = NN;
        while (lo < hi) { int mid = (lo+hi) >> 1; if (g_batch[mid] < g) lo = mid+1; else hi = mid; }
        off[g] = lo;
    }
    __syncthreads();
    if (g < NG) { g_goff[g] = off[g]; g_gcnt[g] = off[g+1] - off[g]; }
}

// ---- mean pool, stage 1: 64 graphs x NCH chunks, float4-vectorized ----
__global__ void k_pool() {
    int g = blockIdx.x / NCH, c = blockIdx.x - g*NCH;
    int cnt = g_gcnt[g], off = g_goff[g];
    int step = (cnt + NCH - 1) / NCH;
    int r0 = c*step, r1 = min(cnt, r0 + step);
    int t = threadIdx.x;
    int ch = (t & 31) * 4;       // float4 channel group
    int rr = t >> 5;             // 8 row-streams per block
    float4 s = {0.f,0.f,0.f,0.f};
    for (int i = r0 + rr; i < r1; i += 8) {
        float4 v = *(const float4*)&g_h[(off + i)*HD + ch];
        s.x += v.x; s.y += v.y; s.z += v.z; s.w += v.w;
    }
    __shared__ float4 sh[256];
    sh[t] = s; __syncthreads();
    if (t < 32) {
        float4 a = sh[t];
        #pragma unroll
        for (int k = 1; k < 8; ++k) {
            float4 b = sh[t + k*32];
            a.x += b.x; a.y += b.y; a.z += b.z; a.w += b.w;
        }
        *(float4*)&g_poolp[(g*NCH + c)*HD + ch] = a;
    }
}

// ---- fused head: pool-reduce + lin1 + lin2 + lin3, one block per graph ----
__global__ void k_head(void* outB) {
    __shared__ float pl[HD], h1[HD], h2[HD];
    int g = blockIdx.x, t = threadIdx.x;   // 128 threads
    float s = 0.f;
    for (int c = 0; c < NCH; ++c) s += g_poolp[(g*NCH + c)*HD + t];
    pl[t] = s / fmaxf((float)g_gcnt[g], 1.f);
    __syncthreads();
    float acc = b2f(g_par[O_L1B + t]);
    for (int k = 0; k < HD; ++k) acc += pl[k] * b2f(g_par[O_L1W + k*HD + t]);
    h1[t] = fmaxf(acc, 0.f);
    __syncthreads();
    acc = b2f(g_par[O_L2B + t]);
    for (int k = 0; k < HD; ++k) acc += h1[k] * b2f(g_par[O_L2W + k*HD + t]);
    h2[t] = fmaxf(acc, 0.f);
    __syncthreads();
    if (t < 10) {
        acc = b2f(g_par[O_L3B + t]);
        for (int k = 0; k < HD; ++k) acc += h2[k] * b2f(g_par[O_L3W + k*10 + t]);
        if (g_f32flag) ((float*)outB)[g*10 + t] = acc;
        else           ((u16*)outB)[g*10 + t] = f2b(acc);
    }
}

extern "C" void kernel_launch(void* const* d_in, const int* in_sizes, int n_in,
                              void* d_out, int out_size, void* d_ws, size_t ws_size,
                              hipStream_t stream) {
    const void* x     = d_in[0];
    const void* ei    = d_in[1];
    const void* batch = d_in[3];

    k_detect<<<1, 64, 0, stream>>>(x, ei);
    k_init<<<NB, 256, 0, stream>>>();
    k_convx<<<6250, 256, 0, stream>>>(x);
    P18 a;
    const int srcidx[18] = {4,5,6,7,8,9,10,11,12,13,14,15,16,17,18,19,20,21};
    const int offs[18] = {O_WEMB,O_BEMB,O_CW,O_CAS,O_CAD,O_CB,O_C2W,O_C2AS,O_C2AD,
                          O_C2B,O_BNG,O_BNB,O_L1W,O_L1B,O_L2W,O_L2B,O_L3W,O_L3B};
    const int lens[18] = {16384,128,32768,256,256,256,16384,128,128,128,384,384,
                          16384,128,16384,128,1280,10};
    for (int t = 0; t < 18; ++t) { a.p[t] = d_in[srcidx[t]]; a.off[t] = offs[t]; a.n[t] = lens[t]; }
    k_convpar<<<64, 256, 0, stream>>>(a);
    k_convidx<<<3125, 256, 0, stream>>>(ei, batch);   // fused edge-count atomics

    k_blocksum<<<NB, 256, 0, stream>>>();
    k_scanb<<<1, 256, 0, stream>>>();
    k_downsweep<<<NB, 256, 0, stream>>>();
    k_scatter<<<NTILE*8, 256, 0, stream>>>();         // XCD-affine partitions
    k_transpose4<<<256, 256, 0, stream>>>();
    k_gidx<<<1, 128, 0, stream>>>();

    // embedding: h = x @ W_emb + b_emb
    k_gemm<<<391, 256, 0, stream>>>(0, 0, O_BEMB, 0, NN);

    for (int L = 0; L < 3; ++L) {
        int heads = (L < 2) ? 8 : 1;
        int ch    = (L < 2) ? 16 : 128;
        int hs    = (L < 2) ? 4 : 7;
        int as    = (L < 2) ? O_CAS + L*128 : O_C2AS;
        int ad    = (L < 2) ? O_CAD + L*128 : O_C2AD;
        int cb    = (L < 2) ? O_CB  + L*128 : O_C2B;
        k_gemm<<<391, 256, 0, stream>>>(1, L+1, -1, 1, NN);
        int atot = NN*heads;
        k_att<<<(atot + 255)/256, 256, 0, stream>>>(as, ad, heads, ch, atot);
        k_flash<<<12500, 256, 0, stream>>>(cb, heads, hs);
        k_bnstats<<<NBN, 256, 0, stream>>>();
        k_bnfinal<<<1, 128, 0, stream>>>(O_BNG + L*HD, O_BNB + L*HD);
        k_bnapply<<<6250, 256, 0, stream>>>();
    }

    k_pool<<<NG*NCH, 256, 0, stream>>>();
    k_head<<<NG, 128, 0, stream>>>(d_out);
}

// Round 8
// 574.444 us; speedup vs baseline: 2.1414x; 1.1252x over previous
//
#include <hip/hip_runtime.h>

// GAT_30039001268364: 3-layer GAT + BN + residual + mean-pool + MLP on MI355X.
// Runtime-adaptive input dtypes (f32-vs-bf16, int64-vs-int32, per-wave ballot probe).

#define NN   50000
#define NE   800000
#define NET  (NE + NN)
#define HD   128
#define NG   64
#define NB   196          // ceil(NN/256)
#define NBN  391          // ceil(NN/128)  — BN stats blocks
#define NCH  20           // pool chunks per graph
#define NTILE 3321        // ceil(NET/256) — edge tiles
#define PSZ  6250         // dst-partition size (8 partitions)

typedef unsigned short u16;
typedef __attribute__((ext_vector_type(8))) short short8;
typedef __attribute__((ext_vector_type(4))) float f32x4;

// ---- canonical parameter pool offsets (bf16 elements) ----
#define O_WEMB 0
#define O_BEMB 16384
#define O_CW   16512
#define O_CAS  49280
#define O_CAD  49536
#define O_CB   49792
#define O_C2W  50048
#define O_C2AS 66432
#define O_C2AD 66560
#define O_C2B  66688
#define O_BNG  66816
#define O_BNB  67200
#define O_L1W  67584
#define O_L1B  83968
#define O_L2W  84096
#define O_L2B  100480
#define O_L3W  100608
#define O_L3B  101888
#define NPAR   101898

// ---- persistent device scratch ----
__device__ int   g_f32flag;
__device__ __align__(16) u16 g_x [NN*HD];
__device__ __align__(16) u16 g_par[NPAR];
__device__ int   g_src[NE], g_dst[NE], g_batch[NN];
__device__ __align__(16) float g_h[NN*HD];
__device__ __align__(16) u16 g_hb[NN*HD];
__device__ __align__(16) u16 g_hw[NN*HD];
__device__ __align__(16) float g_c[NN*HD];
__device__ float g_asrc[NN*8];
__device__ float g_adst[NN*8];
__device__ int   g_rowptr[NN+1];
__device__ int   g_cursor[NN];
__device__ int   g_bsum[NB], g_boff[NB];
__device__ int   g_csr[NET];
__device__ float g_bnp1[NBN*HD], g_bnp2[NBN*HD];
__device__ float g_scl[HD], g_shf[HD];
__device__ int   g_gcnt[NG], g_goff[NG];
__device__ __align__(16) float g_poolp[NG*NCH*HD];
__device__ __align__(16) u16 g_WT[4][HD*HD];

__device__ __forceinline__ float b2f(u16 u) {
    unsigned v = ((unsigned)u) << 16; float f; __builtin_memcpy(&f, &v, 4); return f;
}
__device__ __forceinline__ u16 f2b(float f) {
    unsigned v; __builtin_memcpy(&v, &f, 4);
    return (u16)((v + 0x7fffu + ((v >> 16) & 1u)) >> 16);   // RNE
}

// wave-uniform dtype probes (64 fixed samples, ballot — deterministic)
__device__ __forceinline__ int probe_f32(const void* xp) {
    const u16* p = (const u16*)xp;
    int ex = (p[threadIdx.x & 63] >> 7) & 0xff;
    return __ballot(ex >= 0x93) != 0ULL;   // |v|>=2^20: impossible for bf16 acts
}
__device__ __forceinline__ int probe_i64(const void* eip) {
    const int* q = (const int*)eip;
    return __ballot(q[2*(threadIdx.x & 63) + 1] != 0) == 0ULL; // i64: high words 0
}

// intra-block inclusive scan (256 threads = 4 waves), shuffle-based
__device__ __forceinline__ int block_incl_scan(int v, int* lds4) {
    int t = threadIdx.x, lane = t & 63, w = t >> 6;
    #pragma unroll
    for (int d = 1; d < 64; d <<= 1) {
        int o = __shfl_up(v, d);
        if (lane >= d) v += o;
    }
    if (lane == 63) lds4[w] = v;
    __syncthreads();
    if (w == 0 && lane < 4) {
        int s = lds4[lane];
        #pragma unroll
        for (int d = 1; d < 4; d <<= 1) {
            int o = __shfl_up(s, d);
            if (lane >= d) s += o;
        }
        lds4[lane] = s;
    }
    __syncthreads();
    if (w > 0) v += lds4[w-1];
    return v;
}

// ---- canonicalize x (+ fused cursor init + flag publish) ----
__global__ void k_convx(const void* xp) {    // grid 6250 x 256
    int gi = blockIdx.x*256 + threadIdx.x;
    int f32 = probe_f32(xp);
    if (gi == 0) g_f32flag = f32;
    if (gi < NN) g_cursor[gi] = 1;           // self-loop pre-count
    int i = gi*4;
    if (f32) {
        float4 v = *(const float4*)((const float*)xp + i);
        ushort4 o = { f2b(v.x), f2b(v.y), f2b(v.z), f2b(v.w) };
        *(ushort4*)&g_x[i] = o;
    } else {
        *(ushort4*)&g_x[i] = *(const ushort4*)((const u16*)xp + i);
    }
}
struct P18 { const void* p[18]; int off[18]; int n[18]; };
__global__ void k_convpar(P18 a, const void* xp) {
    int f32 = probe_f32(xp);
    for (int t = 0; t < 18; ++t) {
        const void* s = a.p[t]; int off = a.off[t], n = a.n[t];
        for (int i = blockIdx.x*256 + threadIdx.x; i < n; i += 64*256)
            g_par[off+i] = f32 ? f2b(((const float*)s)[i]) : ((const u16*)s)[i];
    }
}
__global__ void k_convidx(const void* ei, const void* ba) {   // + fused edge count
    int i64 = probe_i64(ei);
    int e = blockIdx.x*256 + threadIdx.x;
    if (e < NE) {
        int s, d;
        if (i64) { s = (int)((const long long*)ei)[e]; d = (int)((const long long*)ei)[NE + e]; }
        else     { s = ((const int*)ei)[e];            d = ((const int*)ei)[NE + e]; }
        g_src[e] = s; g_dst[e] = d;
        atomicAdd(&g_cursor[d], 1);
    }
    if (e < NN)
        g_batch[e] = i64 ? (int)((const long long*)ba)[e] : ((const int*)ba)[e];
}

// ---- hierarchical exclusive scan of degree counts ----
__global__ void k_blocksum() {
    int i = blockIdx.x*256 + threadIdx.x;
    int v = (i < NN) ? g_cursor[i] : 0;
    #pragma unroll
    for (int d = 32; d; d >>= 1) v += __shfl_down(v, d);
    __shared__ int lds[4];
    if ((threadIdx.x & 63) == 0) lds[threadIdx.x >> 6] = v;
    __syncthreads();
    if (threadIdx.x == 0) g_bsum[blockIdx.x] = lds[0]+lds[1]+lds[2]+lds[3];
}
// ---- merged small ops: weight transposes (blocks 0-255), block-sum scan (256),
// ---- graph-offset binary search (257) ----
__global__ void k_misc() {
    int b = blockIdx.x;
    if (b < 256) {
        int which = b >> 6;
        int poff = which==0 ? O_WEMB : which==1 ? O_CW : which==2 ? (O_CW+16384) : O_C2W;
        int idx = (b & 63)*256 + threadIdx.x;
        int n = idx >> 7, k = idx & 127;
        g_WT[which][n*HD + k] = g_par[poff + k*HD + n];
    } else if (b == 256) {
        __shared__ int lds[4];
        int t = threadIdx.x;
        int v = (t < NB) ? g_bsum[t] : 0;
        int incl = block_incl_scan(v, lds);
        if (t < NB) g_boff[t] = incl - v;     // exclusive
    } else {
        __shared__ int off[NG+1];
        int g = threadIdx.x;
        if (g <= NG) {
            int lo = 0, hi = NN;
            while (lo < hi) { int mid = (lo+hi) >> 1; if (g_batch[mid] < g) lo = mid+1; else hi = mid; }
            off[g] = lo;
        }
        __syncthreads();
        if (g < NG) { g_goff[g] = off[g]; g_gcnt[g] = off[g+1] - off[g]; }
    }
}
__global__ void k_downsweep() {
    __shared__ int lds[4];
    int i = blockIdx.x*256 + threadIdx.x;
    int c = (i < NN) ? g_cursor[i] : 0;
    int incl = block_incl_scan(c, lds);
    int base = g_boff[blockIdx.x];
    if (i < NN) {
        g_rowptr[i+1] = base + incl;
        g_cursor[i]   = base + incl - c;  // exclusive start = scatter cursor
    }
    if (i == 0) g_rowptr[0] = 0;
}

// ---- scatter, XCD-affine dst partitioning (round-6: kills 64B-line writeback amp) ----
__global__ void k_scatter() {   // grid NTILE*8
    int part = blockIdx.x & 7;
    int e = (blockIdx.x >> 3)*256 + threadIdx.x;
    if (e >= NET) return;
    int s, d;
    if (e < NE) { s = g_src[e]; d = g_dst[e]; } else { s = d = e - NE; }
    if (d / PSZ != part) return;
    int pos = atomicAdd(&g_cursor[d], 1);
    g_csr[pos] = s;
}

// ---- GEMM + fused attention-logit epilogue ----
// asoff>=0: compute a_src/a_dst per row via m16-group shuffle reduction
// (row r's 128 channels live on the 16 lanes sharing q; head = ct for heads=8).
__global__ __launch_bounds__(256) void k_gemm(int asel, int wsel, int biasoff,
                                              int outmode, int nrows,
                                              int asoff, int adoff, int heads) {
    __shared__ __align__(16) u16 wt[HD*136];
    const u16* A = asel ? g_hb : g_x;
    const u16* WTg = g_WT[wsel];
    int t = threadIdx.x;
    #pragma unroll
    for (int i = 0; i < 8; ++i) {
        int e = (t + i*256) * 8;
        int n = e >> 7, k = e & 127;
        *(uint4*)&wt[n*136 + k] = *(const uint4*)&WTg[e];
    }
    __syncthreads();
    int lane = t & 63, wave = t >> 6;
    int m16 = lane & 15, q = lane >> 4;
    int row0 = blockIdx.x*128 + wave*32;
    f32x4 acc[2][8];
    #pragma unroll
    for (int a = 0; a < 2; ++a)
        #pragma unroll
        for (int b = 0; b < 8; ++b) acc[a][b] = (f32x4){0.f,0.f,0.f,0.f};
    #pragma unroll
    for (int kc = 0; kc < 4; ++kc) {
        short8 af[2];
        #pragma unroll
        for (int rt = 0; rt < 2; ++rt) {
            int r = row0 + rt*16 + m16; if (r > nrows-1) r = nrows-1;
            af[rt] = *(const short8*)&A[r*HD + kc*32 + q*8];
        }
        #pragma unroll
        for (int ct = 0; ct < 8; ++ct) {
            short8 bf = *(const short8*)&wt[(ct*16 + m16)*136 + kc*32 + q*8];
            acc[0][ct] = __builtin_amdgcn_mfma_f32_16x16x32_bf16(af[0], bf, acc[0][ct], 0,0,0);
            acc[1][ct] = __builtin_amdgcn_mfma_f32_16x16x32_bf16(af[1], bf, acc[1][ct], 0,0,0);
        }
    }
    // C/D layout: col = lane&15, row = q*4 + reg
    #pragma unroll
    for (int rt = 0; rt < 2; ++rt)
        #pragma unroll
        for (int reg = 0; reg < 4; ++reg) {
            int r = row0 + rt*16 + q*4 + reg;
            if (r < nrows) {
                #pragma unroll
                for (int ct = 0; ct < 8; ++ct) {
                    int c = ct*16 + m16;
                    float v = acc[rt][ct][reg];
                    if (biasoff >= 0) v += b2f(g_par[biasoff + c]);
                    if (outmode == 0) { g_h[r*HD+c] = v; g_hb[r*HD+c] = f2b(v); }
                    else              { g_hw[r*HD+c] = f2b(v); }
                }
            }
        }
    if (asoff >= 0) {
        #pragma unroll
        for (int rt = 0; rt < 2; ++rt)
            #pragma unroll
            for (int reg = 0; reg < 4; ++reg) {
                float v[8], u[8];
                #pragma unroll
                for (int ct = 0; ct < 8; ++ct) {
                    float w = acc[rt][ct][reg];
                    v[ct] = w * b2f(g_par[asoff + ct*16 + m16]);
                    u[ct] = w * b2f(g_par[adoff + ct*16 + m16]);
                }
                #pragma unroll
                for (int d = 1; d < 16; d <<= 1)
                    #pragma unroll
                    for (int ct = 0; ct < 8; ++ct) {
                        v[ct] += __shfl_xor(v[ct], d);
                        u[ct] += __shfl_xor(u[ct], d);
                    }
                int r = row0 + rt*16 + q*4 + reg;
                if (m16 == 0 && r < nrows) {
                    if (heads == 8) {
                        #pragma unroll
                        for (int h = 0; h < 8; ++h) {
                            g_asrc[r*8 + h] = v[h];
                            g_adst[r*8 + h] = u[h];
                        }
                    } else {
                        float sv = 0.f, su = 0.f;
                        #pragma unroll
                        for (int ct = 0; ct < 8; ++ct) { sv += v[ct]; su += u[ct]; }
                        g_asrc[r] = sv; g_adst[r] = su;
                    }
                }
            }
    }
}

// ---- segment softmax + aggregate: one wave per dst node, 8/4/1 edge batching ----
__global__ __launch_bounds__(256) void k_flash(int boff, int heads, int hs) {
    int node = blockIdx.x*4 + (threadIdx.x >> 6);
    int lane = threadIdx.x & 63;
    int c0 = lane*2;
    int head = c0 >> hs;
    float ad = g_adst[node*heads + head];
    int beg = g_rowptr[node], end = g_rowptr[node+1];
    float l = 0.f, o0 = 0.f, o1 = 0.f;
    int j = beg;
    for (; j + 8 <= end; j += 8) {
        int s[8]; float av[8]; unsigned w[8];
        #pragma unroll
        for (int k = 0; k < 8; ++k) s[k] = g_csr[j+k];
        #pragma unroll
        for (int k = 0; k < 8; ++k) av[k] = g_asrc[s[k]*heads + head];
        #pragma unroll
        for (int k = 0; k < 8; ++k) w[k] = *(const unsigned*)&g_hw[s[k]*HD + c0];
        #pragma unroll
        for (int k = 0; k < 8; ++k) {
            float e = av[k] + ad;
            e = fmaxf(e, 0.2f*e);
            float p = __expf(fminf(e, 30.f));
            l  += p;
            o0 += p*b2f((u16)(w[k] & 0xffff));
            o1 += p*b2f((u16)(w[k] >> 16));
        }
    }
    for (; j + 4 <= end; j += 4) {
        int s[4]; float av[4]; unsigned w[4];
        #pragma unroll
        for (int k = 0; k < 4; ++k) s[k] = g_csr[j+k];
        #pragma unroll
        for (int k = 0; k < 4; ++k) av[k] = g_asrc[s[k]*heads + head];
        #pragma unroll
        for (int k = 0; k < 4; ++k) w[k] = *(const unsigned*)&g_hw[s[k]*HD + c0];
        #pragma unroll
        for (int k = 0; k < 4; ++k) {
            float e = av[k] + ad;
            e = fmaxf(e, 0.2f*e);
            float p = __expf(fminf(e, 30.f));
            l  += p;
            o0 += p*b2f((u16)(w[k] & 0xffff));
            o1 += p*b2f((u16)(w[k] >> 16));
        }
    }
    for (; j < end; ++j) {
        int s = g_csr[j];
        float e = g_asrc[s*heads + head] + ad;
        e = fmaxf(e, 0.2f*e);
        float p = __expf(fminf(e, 30.f));
        unsigned w = *(const unsigned*)&g_hw[s*HD + c0];
        l  += p;
        o0 += p*b2f((u16)(w & 0xffff));
        o1 += p*b2f((u16)(w >> 16));
    }
    float inv = 1.f/l;                       // l>0: self-loop guarantees >=1 edge
    g_c[node*HD + c0]     = o0*inv + b2f(g_par[boff + c0]);
    g_c[node*HD + c0 + 1] = o1*inv + b2f(g_par[boff + c0 + 1]);
}

// ---- BatchNorm: per-block partials + parallel reduce ----
__global__ void k_bnstats() {
    int t = threadIdx.x; int ch = t & 127, r0 = t >> 7;
    int base = blockIdx.x*128;
    float s = 0.f, q = 0.f;
    for (int i = r0; i < 128; i += 2) {
        int n = base + i;
        if (n < NN) { float v = g_c[n*HD + ch]; s += v; q += v*v; }
    }
    __shared__ float sS[256], sQ[256];
    sS[t] = s; sQ[t] = q; __syncthreads();
    if (t < 128) {
        g_bnp1[blockIdx.x*HD + t] = sS[t] + sS[t+128];
        g_bnp2[blockIdx.x*HD + t] = sQ[t] + sQ[t+128];
    }
}
__global__ void k_bnfinal(int goff, int boff) {   // 128 blocks x 64
    int ch = blockIdx.x, t = threadIdx.x;
    float s = 0.f, q = 0.f;
    for (int b = t; b < NBN; b += 64) { s += g_bnp1[b*HD + ch]; q += g_bnp2[b*HD + ch]; }
    #pragma unroll
    for (int d = 32; d; d >>= 1) { s += __shfl_down(s, d); q += __shfl_down(q, d); }
    if (t == 0) {
        float mean = s / (float)NN;
        float var  = fmaxf(q / (float)NN - mean*mean, 0.f);
        float sc = b2f(g_par[goff + ch]) * rsqrtf(var + 1e-5f);
        g_scl[ch] = sc;
        g_shf[ch] = b2f(g_par[boff + ch]) - mean*sc;
    }
}
__global__ void k_bnapply(int writeb) {   // grid 6250 x 256, x4 vectorized
    int i = (blockIdx.x*256 + threadIdx.x)*4;
    int ch = i & 127;
    float4 c = *(const float4*)&g_c[i];
    float4 h = *(const float4*)&g_h[i];
    float4 r;
    r.x = fmaxf(c.x*g_scl[ch  ] + g_shf[ch  ], 0.f) + h.x;
    r.y = fmaxf(c.y*g_scl[ch+1] + g_shf[ch+1], 0.f) + h.y;
    r.z = fmaxf(c.z*g_scl[ch+2] + g_shf[ch+2], 0.f) + h.z;
    r.w = fmaxf(c.w*g_scl[ch+3] + g_shf[ch+3], 0.f) + h.w;
    *(float4*)&g_h[i] = r;
    if (writeb) {
        ushort4 o = { f2b(r.x), f2b(r.y), f2b(r.z), f2b(r.w) };
        *(ushort4*)&g_hb[i] = o;
    }
}

// ---- mean pool, stage 1: 64 graphs x NCH chunks, float4-vectorized ----
__global__ void k_pool() {
    int g = blockIdx.x / NCH, c = blockIdx.x - g*NCH;
    int cnt = g_gcnt[g], off = g_goff[g];
    int step = (cnt + NCH - 1) / NCH;
    int r0 = c*step, r1 = min(cnt, r0 + step);
    int t = threadIdx.x;
    int ch = (t & 31) * 4;
    int rr = t >> 5;
    float4 s = {0.f,0.f,0.f,0.f};
    for (int i = r0 + rr; i < r1; i += 8) {
        float4 v = *(const float4*)&g_h[(off + i)*HD + ch];
        s.x += v.x; s.y += v.y; s.z += v.z; s.w += v.w;
    }
    __shared__ float4 sh[256];
    sh[t] = s; __syncthreads();
    if (t < 32) {
        float4 a = sh[t];
        #pragma unroll
        for (int k = 1; k < 8; ++k) {
            float4 b = sh[t + k*32];
            a.x += b.x; a.y += b.y; a.z += b.z; a.w += b.w;
        }
        *(float4*)&g_poolp[(g*NCH + c)*HD + ch] = a;
    }
}

// ---- fused head: pool-reduce + lin1 + lin2 + lin3, one block per graph ----
__global__ void k_head(void* outB) {
    __shared__ float pl[HD], h1[HD], h2[HD];
    int g = blockIdx.x, t = threadIdx.x;   // 128 threads
    float s = 0.f;
    for (int c = 0; c < NCH; ++c) s += g_poolp[(g*NCH + c)*HD + t];
    pl[t] = s / fmaxf((float)g_gcnt[g], 1.f);
    __syncthreads();
    float acc = b2f(g_par[O_L1B + t]);
    for (int k = 0; k < HD; ++k) acc += pl[k] * b2f(g_par[O_L1W + k*HD + t]);
    h1[t] = fmaxf(acc, 0.f);
    __syncthreads();
    acc = b2f(g_par[O_L2B + t]);
    for (int k = 0; k < HD; ++k) acc += h1[k] * b2f(g_par[O_L2W + k*HD + t]);
    h2[t] = fmaxf(acc, 0.f);
    __syncthreads();
    if (t < 10) {
        acc = b2f(g_par[O_L3B + t]);
        for (int k = 0; k < HD; ++k) acc += h2[k] * b2f(g_par[O_L3W + k*10 + t]);
        if (g_f32flag) ((float*)outB)[g*10 + t] = acc;
        else           ((u16*)outB)[g*10 + t] = f2b(acc);
    }
}

extern "C" void kernel_launch(void* const* d_in, const int* in_sizes, int n_in,
                              void* d_out, int out_size, void* d_ws, size_t ws_size,
                              hipStream_t stream) {
    const void* x     = d_in[0];
    const void* ei    = d_in[1];
    const void* batch = d_in[3];

    k_convx<<<6250, 256, 0, stream>>>(x);            // + cursor init + flag
    P18 a;
    const int srcidx[18] = {4,5,6,7,8,9,10,11,12,13,14,15,16,17,18,19,20,21};
    const int offs[18] = {O_WEMB,O_BEMB,O_CW,O_CAS,O_CAD,O_CB,O_C2W,O_C2AS,O_C2AD,
                          O_C2B,O_BNG,O_BNB,O_L1W,O_L1B,O_L2W,O_L2B,O_L3W,O_L3B};
    const int lens[18] = {16384,128,32768,256,256,256,16384,128,128,128,384,384,
                          16384,128,16384,128,1280,10};
    for (int t = 0; t < 18; ++t) { a.p[t] = d_in[srcidx[t]]; a.off[t] = offs[t]; a.n[t] = lens[t]; }
    k_convpar<<<64, 256, 0, stream>>>(a, x);
    k_convidx<<<3125, 256, 0, stream>>>(ei, batch);  // + edge-count atomics

    k_blocksum<<<NB, 256, 0, stream>>>();
    k_misc<<<258, 256, 0, stream>>>();               // transpose + scanb + gidx
    k_downsweep<<<NB, 256, 0, stream>>>();
    k_scatter<<<NTILE*8, 256, 0, stream>>>();        // XCD-affine partitions

    // embedding: h = x @ W_emb + b_emb
    k_gemm<<<391, 256, 0, stream>>>(0, 0, O_BEMB, 0, NN, -1, -1, 0);

    for (int L = 0; L < 3; ++L) {
        int heads = (L < 2) ? 8 : 1;
        int hs    = (L < 2) ? 4 : 7;
        int as    = (L < 2) ? O_CAS + L*128 : O_C2AS;
        int ad    = (L < 2) ? O_CAD + L*128 : O_C2AD;
        int cb    = (L < 2) ? O_CB  + L*128 : O_C2B;
        k_gemm<<<391, 256, 0, stream>>>(1, L+1, -1, 1, NN, as, ad, heads);  // + att epilogue
        k_flash<<<12500, 256, 0, stream>>>(cb, heads, hs);
        k_bnstats<<<NBN, 256, 0, stream>>>();
        k_bnfinal<<<128, 64, 0, stream>>>(O_BNG + L*HD, O_BNB + L*HD);
        k_bnapply<<<6250, 256, 0, stream>>>(L < 2 ? 1 : 0);
    }

    k_pool<<<NG*NCH, 256, 0, stream>>>();
    k_head<<<NG, 128, 0, stream>>>(d_out);
}

// Round 9
// 552.883 us; speedup vs baseline: 2.2249x; 1.0390x over previous
//
#include <hip/hip_runtime.h>

// GAT_30039001268364: 3-layer GAT + BN + residual + mean-pool + MLP on MI355X.
// Runtime-adaptive input dtypes (f32-vs-bf16, int64-vs-int32, per-wave ballot probe).
// R9: g_c stored bf16; BN+ReLU+residual fused into next GEMM's A-prologue (and
// into k_pool for the last layer) — k_bnapply eliminated.

#define NN   50000
#define NE   800000
#define NET  (NE + NN)
#define HD   128
#define NG   64
#define NB   196          // ceil(NN/256)
#define NBN  391          // ceil(NN/128)  — BN stats blocks
#define NCH  20           // pool chunks per graph
#define NTILE 3321        // ceil(NET/256) — edge tiles
#define PSZ  6250         // dst-partition size (8 partitions)

typedef unsigned short u16;
typedef __attribute__((ext_vector_type(8))) short short8;
typedef __attribute__((ext_vector_type(4))) float f32x4;

// ---- canonical parameter pool offsets (bf16 elements) ----
#define O_WEMB 0
#define O_BEMB 16384
#define O_CW   16512
#define O_CAS  49280
#define O_CAD  49536
#define O_CB   49792
#define O_C2W  50048
#define O_C2AS 66432
#define O_C2AD 66560
#define O_C2B  66688
#define O_BNG  66816
#define O_BNB  67200
#define O_L1W  67584
#define O_L1B  83968
#define O_L2W  84096
#define O_L2B  100480
#define O_L3W  100608
#define O_L3B  101888
#define NPAR   101898

// ---- persistent device scratch ----
__device__ int   g_f32flag;
__device__ __align__(16) u16 g_x [NN*HD];
__device__ __align__(16) u16 g_par[NPAR];
__device__ int   g_src[NE], g_dst[NE], g_batch[NN];
__device__ __align__(16) float g_h[NN*HD];
__device__ __align__(16) u16 g_hb[NN*HD];   // embed output bf16 (gemm0 A input)
__device__ __align__(16) u16 g_hw[NN*HD];
__device__ __align__(16) u16 g_c[NN*HD];    // conv output, bf16 (R9)
__device__ float g_asrc[NN*8];
__device__ float g_adst[NN*8];
__device__ int   g_rowptr[NN+1];
__device__ int   g_cursor[NN];
__device__ int   g_bsum[NB], g_boff[NB];
__device__ int   g_csr[NET];
__device__ float g_bnp1[NBN*HD], g_bnp2[NBN*HD];
__device__ float g_scl[HD], g_shf[HD];
__device__ int   g_gcnt[NG], g_goff[NG];
__device__ __align__(16) float g_poolp[NG*NCH*HD];
__device__ __align__(16) u16 g_WT[4][HD*HD];

__device__ __forceinline__ float b2f(u16 u) {
    unsigned v = ((unsigned)u) << 16; float f; __builtin_memcpy(&f, &v, 4); return f;
}
__device__ __forceinline__ u16 f2b(float f) {
    unsigned v; __builtin_memcpy(&v, &f, 4);
    return (u16)((v + 0x7fffu + ((v >> 16) & 1u)) >> 16);   // RNE
}

// wave-uniform dtype probes (64 fixed samples, ballot — deterministic)
__device__ __forceinline__ int probe_f32(const void* xp) {
    const u16* p = (const u16*)xp;
    int ex = (p[threadIdx.x & 63] >> 7) & 0xff;
    return __ballot(ex >= 0x93) != 0ULL;   // |v|>=2^20: impossible for bf16 acts
}
__device__ __forceinline__ int probe_i64(const void* eip) {
    const int* q = (const int*)eip;
    return __ballot(q[2*(threadIdx.x & 63) + 1] != 0) == 0ULL; // i64: high words 0
}

// intra-block inclusive scan (256 threads = 4 waves), shuffle-based
__device__ __forceinline__ int block_incl_scan(int v, int* lds4) {
    int t = threadIdx.x, lane = t & 63, w = t >> 6;
    #pragma unroll
    for (int d = 1; d < 64; d <<= 1) {
        int o = __shfl_up(v, d);
        if (lane >= d) v += o;
    }
    if (lane == 63) lds4[w] = v;
    __syncthreads();
    if (w == 0 && lane < 4) {
        int s = lds4[lane];
        #pragma unroll
        for (int d = 1; d < 4; d <<= 1) {
            int o = __shfl_up(s, d);
            if (lane >= d) s += o;
        }
        lds4[lane] = s;
    }
    __syncthreads();
    if (w > 0) v += lds4[w-1];
    return v;
}

// ---- canonicalize x (+ fused cursor init + flag publish) ----
__global__ void k_convx(const void* xp) {    // grid 6250 x 256
    int gi = blockIdx.x*256 + threadIdx.x;
    int f32 = probe_f32(xp);
    if (gi == 0) g_f32flag = f32;
    if (gi < NN) g_cursor[gi] = 1;           // self-loop pre-count
    int i = gi*4;
    if (f32) {
        float4 v = *(const float4*)((const float*)xp + i);
        ushort4 o = { f2b(v.x), f2b(v.y), f2b(v.z), f2b(v.w) };
        *(ushort4*)&g_x[i] = o;
    } else {
        *(ushort4*)&g_x[i] = *(const ushort4*)((const u16*)xp + i);
    }
}
struct P18 { const void* p[18]; int off[18]; int n[18]; };
__global__ void k_convpar(P18 a, const void* xp) {
    int f32 = probe_f32(xp);
    for (int t = 0; t < 18; ++t) {
        const void* s = a.p[t]; int off = a.off[t], n = a.n[t];
        for (int i = blockIdx.x*256 + threadIdx.x; i < n; i += 64*256)
            g_par[off+i] = f32 ? f2b(((const float*)s)[i]) : ((const u16*)s)[i];
    }
}
__global__ void k_convidx(const void* ei, const void* ba) {   // + fused edge count
    int i64 = probe_i64(ei);
    int e = blockIdx.x*256 + threadIdx.x;
    if (e < NE) {
        int s, d;
        if (i64) { s = (int)((const long long*)ei)[e]; d = (int)((const long long*)ei)[NE + e]; }
        else     { s = ((const int*)ei)[e];            d = ((const int*)ei)[NE + e]; }
        g_src[e] = s; g_dst[e] = d;
        atomicAdd(&g_cursor[d], 1);
    }
    if (e < NN)
        g_batch[e] = i64 ? (int)((const long long*)ba)[e] : ((const int*)ba)[e];
}

// ---- hierarchical exclusive scan of degree counts ----
__global__ void k_blocksum() {
    int i = blockIdx.x*256 + threadIdx.x;
    int v = (i < NN) ? g_cursor[i] : 0;
    #pragma unroll
    for (int d = 32; d; d >>= 1) v += __shfl_down(v, d);
    __shared__ int lds[4];
    if ((threadIdx.x & 63) == 0) lds[threadIdx.x >> 6] = v;
    __syncthreads();
    if (threadIdx.x == 0) g_bsum[blockIdx.x] = lds[0]+lds[1]+lds[2]+lds[3];
}
// ---- merged small ops: weight transposes (0-255), scan (256), graph offsets (257) ----
__global__ void k_misc() {
    int b = blockIdx.x;
    if (b < 256) {
        int which = b >> 6;
        int poff = which==0 ? O_WEMB : which==1 ? O_CW : which==2 ? (O_CW+16384) : O_C2W;
        int idx = (b & 63)*256 + threadIdx.x;
        int n = idx >> 7, k = idx & 127;
        g_WT[which][n*HD + k] = g_par[poff + k*HD + n];
    } else if (b == 256) {
        __shared__ int lds[4];
        int t = threadIdx.x;
        int v = (t < NB) ? g_bsum[t] : 0;
        int incl = block_incl_scan(v, lds);
        if (t < NB) g_boff[t] = incl - v;     // exclusive
    } else {
        __shared__ int off[NG+1];
        int g = threadIdx.x;
        if (g <= NG) {
            int lo = 0, hi = NN;
            while (lo < hi) { int mid = (lo+hi) >> 1; if (g_batch[mid] < g) lo = mid+1; else hi = mid; }
            off[g] = lo;
        }
        __syncthreads();
        if (g < NG) { g_goff[g] = off[g]; g_gcnt[g] = off[g+1] - off[g]; }
    }
}
__global__ void k_downsweep() {
    __shared__ int lds[4];
    int i = blockIdx.x*256 + threadIdx.x;
    int c = (i < NN) ? g_cursor[i] : 0;
    int incl = block_incl_scan(c, lds);
    int base = g_boff[blockIdx.x];
    if (i < NN) {
        g_rowptr[i+1] = base + incl;
        g_cursor[i]   = base + incl - c;  // exclusive start = scatter cursor
    }
    if (i == 0) g_rowptr[0] = 0;
}

// ---- scatter, XCD-affine dst partitioning (kills 64B-line writeback amp) ----
__global__ void k_scatter() {   // grid NTILE*8
    int part = blockIdx.x & 7;
    int e = (blockIdx.x >> 3)*256 + threadIdx.x;
    if (e >= NET) return;
    int s, d;
    if (e < NE) { s = g_src[e]; d = g_dst[e]; } else { s = d = e - NE; }
    if (d / PSZ != part) return;
    int pos = atomicAdd(&g_cursor[d], 1);
    g_csr[pos] = s;
}

// ---- GEMM + fused BN-apply prologue + fused attention-logit epilogue ----
// bnfuse: A rows computed on the fly as h' = relu(c*scl+shf) + h (reads g_c bf16
// + g_h f32, writes g_h back — each row element is touched by exactly one lane;
// clamped duplicate rows write identical values, benign).
// asoff>=0: a_src/a_dst per row via m16-group shuffle reduction (head = ct).
__global__ __launch_bounds__(256) void k_gemm(int asel, int wsel, int biasoff,
                                              int outmode, int nrows,
                                              int asoff, int adoff, int heads,
                                              int bnfuse) {
    __shared__ __align__(16) u16 wt[HD*136];
    __shared__ float s_scl[HD], s_shf[HD];
    const u16* A = asel ? g_hb : g_x;
    const u16* WTg = g_WT[wsel];
    int t = threadIdx.x;
    #pragma unroll
    for (int i = 0; i < 8; ++i) {
        int e = (t + i*256) * 8;
        int n = e >> 7, k = e & 127;
        *(uint4*)&wt[n*136 + k] = *(const uint4*)&WTg[e];
    }
    if (bnfuse && t < HD) { s_scl[t] = g_scl[t]; s_shf[t] = g_shf[t]; }
    __syncthreads();
    int lane = t & 63, wave = t >> 6;
    int m16 = lane & 15, q = lane >> 4;
    int row0 = blockIdx.x*128 + wave*32;
    f32x4 acc[2][8];
    #pragma unroll
    for (int a = 0; a < 2; ++a)
        #pragma unroll
        for (int b = 0; b < 8; ++b) acc[a][b] = (f32x4){0.f,0.f,0.f,0.f};
    #pragma unroll
    for (int kc = 0; kc < 4; ++kc) {
        short8 af[2];
        #pragma unroll
        for (int rt = 0; rt < 2; ++rt) {
            int r = row0 + rt*16 + m16; if (r > nrows-1) r = nrows-1;
            int base = r*HD + kc*32 + q*8;
            if (bnfuse) {
                short8 cv = *(const short8*)&g_c[base];
                float4 h0 = *(const float4*)&g_h[base];
                float4 h1 = *(const float4*)&g_h[base+4];
                float nh[8];
                #pragma unroll
                for (int k2 = 0; k2 < 8; ++k2) {
                    int ch = kc*32 + q*8 + k2;
                    float hv = (k2 < 4) ? (&h0.x)[k2] : (&h1.x)[k2-4];
                    float v = fmaxf(b2f((u16)cv[k2])*s_scl[ch] + s_shf[ch], 0.f) + hv;
                    nh[k2] = v;
                    af[rt][k2] = (short)f2b(v);
                }
                float4 o0 = {nh[0],nh[1],nh[2],nh[3]};
                float4 o1 = {nh[4],nh[5],nh[6],nh[7]};
                *(float4*)&g_h[base]   = o0;
                *(float4*)&g_h[base+4] = o1;
            } else {
                af[rt] = *(const short8*)&A[base];
            }
        }
        #pragma unroll
        for (int ct = 0; ct < 8; ++ct) {
            short8 bf = *(const short8*)&wt[(ct*16 + m16)*136 + kc*32 + q*8];
            acc[0][ct] = __builtin_amdgcn_mfma_f32_16x16x32_bf16(af[0], bf, acc[0][ct], 0,0,0);
            acc[1][ct] = __builtin_amdgcn_mfma_f32_16x16x32_bf16(af[1], bf, acc[1][ct], 0,0,0);
        }
    }
    // C/D layout: col = lane&15, row = q*4 + reg
    #pragma unroll
    for (int rt = 0; rt < 2; ++rt)
        #pragma unroll
        for (int reg = 0; reg < 4; ++reg) {
            int r = row0 + rt*16 + q*4 + reg;
            if (r < nrows) {
                #pragma unroll
                for (int ct = 0; ct < 8; ++ct) {
                    int c = ct*16 + m16;
                    float v = acc[rt][ct][reg];
                    if (biasoff >= 0) v += b2f(g_par[biasoff + c]);
                    if (outmode == 0) { g_h[r*HD+c] = v; g_hb[r*HD+c] = f2b(v); }
                    else              { g_hw[r*HD+c] = f2b(v); }
                }
            }
        }
    if (asoff >= 0) {
        #pragma unroll
        for (int rt = 0; rt < 2; ++rt)
            #pragma unroll
            for (int reg = 0; reg < 4; ++reg) {
                float v[8], u[8];
                #pragma unroll
                for (int ct = 0; ct < 8; ++ct) {
                    float w = acc[rt][ct][reg];
                    v[ct] = w * b2f(g_par[asoff + ct*16 + m16]);
                    u[ct] = w * b2f(g_par[adoff + ct*16 + m16]);
                }
                #pragma unroll
                for (int d = 1; d < 16; d <<= 1)
                    #pragma unroll
                    for (int ct = 0; ct < 8; ++ct) {
                        v[ct] += __shfl_xor(v[ct], d);
                        u[ct] += __shfl_xor(u[ct], d);
                    }
                int r = row0 + rt*16 + q*4 + reg;
                if (m16 == 0 && r < nrows) {
                    if (heads == 8) {
                        #pragma unroll
                        for (int h = 0; h < 8; ++h) {
                            g_asrc[r*8 + h] = v[h];
                            g_adst[r*8 + h] = u[h];
                        }
                    } else {
                        float sv = 0.f, su = 0.f;
                        #pragma unroll
                        for (int ct = 0; ct < 8; ++ct) { sv += v[ct]; su += u[ct]; }
                        g_asrc[r] = sv; g_adst[r] = su;
                    }
                }
            }
    }
}

// ---- segment softmax + aggregate: one wave per dst node, 8/4/1 edge batching ----
__global__ __launch_bounds__(256) void k_flash(int boff, int heads, int hs) {
    int node = blockIdx.x*4 + (threadIdx.x >> 6);
    int lane = threadIdx.x & 63;
    int c0 = lane*2;
    int head = c0 >> hs;
    float ad = g_adst[node*heads + head];
    int beg = g_rowptr[node], end = g_rowptr[node+1];
    float l = 0.f, o0 = 0.f, o1 = 0.f;
    int j = beg;
    for (; j + 8 <= end; j += 8) {
        int s[8]; float av[8]; unsigned w[8];
        #pragma unroll
        for (int k = 0; k < 8; ++k) s[k] = g_csr[j+k];
        #pragma unroll
        for (int k = 0; k < 8; ++k) av[k] = g_asrc[s[k]*heads + head];
        #pragma unroll
        for (int k = 0; k < 8; ++k) w[k] = *(const unsigned*)&g_hw[s[k]*HD + c0];
        #pragma unroll
        for (int k = 0; k < 8; ++k) {
            float e = av[k] + ad;
            e = fmaxf(e, 0.2f*e);
            float p = __expf(fminf(e, 30.f));
            l  += p;
            o0 += p*b2f((u16)(w[k] & 0xffff));
            o1 += p*b2f((u16)(w[k] >> 16));
        }
    }
    for (; j + 4 <= end; j += 4) {
        int s[4]; float av[4]; unsigned w[4];
        #pragma unroll
        for (int k = 0; k < 4; ++k) s[k] = g_csr[j+k];
        #pragma unroll
        for (int k = 0; k < 4; ++k) av[k] = g_asrc[s[k]*heads + head];
        #pragma unroll
        for (int k = 0; k < 4; ++k) w[k] = *(const unsigned*)&g_hw[s[k]*HD + c0];
        #pragma unroll
        for (int k = 0; k < 4; ++k) {
            float e = av[k] + ad;
            e = fmaxf(e, 0.2f*e);
            float p = __expf(fminf(e, 30.f));
            l  += p;
            o0 += p*b2f((u16)(w[k] & 0xffff));
            o1 += p*b2f((u16)(w[k] >> 16));
        }
    }
    for (; j < end; ++j) {
        int s = g_csr[j];
        float e = g_asrc[s*heads + head] + ad;
        e = fmaxf(e, 0.2f*e);
        float p = __expf(fminf(e, 30.f));
        unsigned w = *(const unsigned*)&g_hw[s*HD + c0];
        l  += p;
        o0 += p*b2f((u16)(w & 0xffff));
        o1 += p*b2f((u16)(w >> 16));
    }
    float inv = 1.f/l;                       // l>0: self-loop guarantees >=1 edge
    ushort2 o = { f2b(o0*inv + b2f(g_par[boff + c0])),
                  f2b(o1*inv + b2f(g_par[boff + c0 + 1])) };
    *(ushort2*)&g_c[node*HD + c0] = o;       // bf16 store (R9)
}

// ---- BatchNorm: per-block partials + parallel reduce ----
__global__ void k_bnstats() {
    int t = threadIdx.x; int ch = t & 127, r0 = t >> 7;
    int base = blockIdx.x*128;
    float s = 0.f, q = 0.f;
    for (int i = r0; i < 128; i += 2) {
        int n = base + i;
        if (n < NN) { float v = b2f(g_c[n*HD + ch]); s += v; q += v*v; }
    }
    __shared__ float sS[256], sQ[256];
    sS[t] = s; sQ[t] = q; __syncthreads();
    if (t < 128) {
        g_bnp1[blockIdx.x*HD + t] = sS[t] + sS[t+128];
        g_bnp2[blockIdx.x*HD + t] = sQ[t] + sQ[t+128];
    }
}
__global__ void k_bnfinal(int goff, int boff) {   // 128 blocks x 64
    int ch = blockIdx.x, t = threadIdx.x;
    float s = 0.f, q = 0.f;
    for (int b = t; b < NBN; b += 64) { s += g_bnp1[b*HD + ch]; q += g_bnp2[b*HD + ch]; }
    #pragma unroll
    for (int d = 32; d; d >>= 1) { s += __shfl_down(s, d); q += __shfl_down(q, d); }
    if (t == 0) {
        float mean = s / (float)NN;
        float var  = fmaxf(q / (float)NN - mean*mean, 0.f);
        float sc = b2f(g_par[goff + ch]) * rsqrtf(var + 1e-5f);
        g_scl[ch] = sc;
        g_shf[ch] = b2f(g_par[boff + ch]) - mean*sc;
    }
}

// ---- mean pool, stage 1 + fused layer-2 BN/ReLU/residual ----
__global__ void k_pool() {
    int g = blockIdx.x / NCH, c = blockIdx.x - g*NCH;
    int cnt = g_gcnt[g], off = g_goff[g];
    int step = (cnt + NCH - 1) / NCH;
    int r0 = c*step, r1 = min(cnt, r0 + step);
    int t = threadIdx.x;
    int ch = (t & 31) * 4;
    int rr = t >> 5;
    float sc0 = g_scl[ch], sc1 = g_scl[ch+1], sc2 = g_scl[ch+2], sc3 = g_scl[ch+3];
    float sf0 = g_shf[ch], sf1 = g_shf[ch+1], sf2 = g_shf[ch+2], sf3 = g_shf[ch+3];
    float4 s = {0.f,0.f,0.f,0.f};
    for (int i = r0 + rr; i < r1; i += 8) {
        int base = (off + i)*HD + ch;
        ushort4 cv = *(const ushort4*)&g_c[base];
        float4 hv = *(const float4*)&g_h[base];
        s.x += fmaxf(b2f(cv.x)*sc0 + sf0, 0.f) + hv.x;
        s.y += fmaxf(b2f(cv.y)*sc1 + sf1, 0.f) + hv.y;
        s.z += fmaxf(b2f(cv.z)*sc2 + sf2, 0.f) + hv.z;
        s.w += fmaxf(b2f(cv.w)*sc3 + sf3, 0.f) + hv.w;
    }
    __shared__ float4 sh[256];
    sh[t] = s; __syncthreads();
    if (t < 32) {
        float4 a = sh[t];
        #pragma unroll
        for (int k = 1; k < 8; ++k) {
            float4 b = sh[t + k*32];
            a.x += b.x; a.y += b.y; a.z += b.z; a.w += b.w;
        }
        *(float4*)&g_poolp[(g*NCH + c)*HD + ch] = a;
    }
}

// ---- fused head: pool-reduce + lin1 + lin2 + lin3, one block per graph ----
__global__ void k_head(void* outB) {
    __shared__ float pl[HD], h1[HD], h2[HD];
    int g = blockIdx.x, t = threadIdx.x;   // 128 threads
    float s = 0.f;
    for (int c = 0; c < NCH; ++c) s += g_poolp[(g*NCH + c)*HD + t];
    pl[t] = s / fmaxf((float)g_gcnt[g], 1.f);
    __syncthreads();
    float acc = b2f(g_par[O_L1B + t]);
    for (int k = 0; k < HD; ++k) acc += pl[k] * b2f(g_par[O_L1W + k*HD + t]);
    h1[t] = fmaxf(acc, 0.f);
    __syncthreads();
    acc = b2f(g_par[O_L2B + t]);
    for (int k = 0; k < HD; ++k) acc += h1[k] * b2f(g_par[O_L2W + k*HD + t]);
    h2[t] = fmaxf(acc, 0.f);
    __syncthreads();
    if (t < 10) {
        acc = b2f(g_par[O_L3B + t]);
        for (int k = 0; k < HD; ++k) acc += h2[k] * b2f(g_par[O_L3W + k*10 + t]);
        if (g_f32flag) ((float*)outB)[g*10 + t] = acc;
        else           ((u16*)outB)[g*10 + t] = f2b(acc);
    }
}

extern "C" void kernel_launch(void* const* d_in, const int* in_sizes, int n_in,
                              void* d_out, int out_size, void* d_ws, size_t ws_size,
                              hipStream_t stream) {
    const void* x     = d_in[0];
    const void* ei    = d_in[1];
    const void* batch = d_in[3];

    k_convx<<<6250, 256, 0, stream>>>(x);            // + cursor init + flag
    P18 a;
    const int srcidx[18] = {4,5,6,7,8,9,10,11,12,13,14,15,16,17,18,19,20,21};
    const int offs[18] = {O_WEMB,O_BEMB,O_CW,O_CAS,O_CAD,O_CB,O_C2W,O_C2AS,O_C2AD,
                          O_C2B,O_BNG,O_BNB,O_L1W,O_L1B,O_L2W,O_L2B,O_L3W,O_L3B};
    const int lens[18] = {16384,128,32768,256,256,256,16384,128,128,128,384,384,
                          16384,128,16384,128,1280,10};
    for (int t = 0; t < 18; ++t) { a.p[t] = d_in[srcidx[t]]; a.off[t] = offs[t]; a.n[t] = lens[t]; }
    k_convpar<<<64, 256, 0, stream>>>(a, x);
    k_convidx<<<3125, 256, 0, stream>>>(ei, batch);  // + edge-count atomics

    k_blocksum<<<NB, 256, 0, stream>>>();
    k_misc<<<258, 256, 0, stream>>>();               // transpose + scanb + gidx
    k_downsweep<<<NB, 256, 0, stream>>>();
    k_scatter<<<NTILE*8, 256, 0, stream>>>();        // XCD-affine partitions

    // embedding: h = x @ W_emb + b_emb  (writes g_h f32 + g_hb bf16)
    k_gemm<<<391, 256, 0, stream>>>(0, 0, O_BEMB, 0, NN, -1, -1, 0, 0);

    for (int L = 0; L < 3; ++L) {
        int heads = (L < 2) ? 8 : 1;
        int hs    = (L < 2) ? 4 : 7;
        int as    = (L < 2) ? O_CAS + L*128 : O_C2AS;
        int ad    = (L < 2) ? O_CAD + L*128 : O_C2AD;
        int cb    = (L < 2) ? O_CB  + L*128 : O_C2B;
        // L>0: BN(L-1)+ReLU+residual fused into A-prologue (scl/shf hold L-1)
        k_gemm<<<391, 256, 0, stream>>>(1, L+1, -1, 1, NN, as, ad, heads, L > 0 ? 1 : 0);
        k_flash<<<12500, 256, 0, stream>>>(cb, heads, hs);
        k_bnstats<<<NBN, 256, 0, stream>>>();
        k_bnfinal<<<128, 64, 0, stream>>>(O_BNG + L*HD, O_BNB + L*HD);
    }

    k_pool<<<NG*NCH, 256, 0, stream>>>();            // + fused layer-2 BN/residual
    k_head<<<NG, 128, 0, stream>>>(d_out);
}

// Round 10
// 536.263 us; speedup vs baseline: 2.2939x; 1.0310x over previous
//
#include <hip/hip_runtime.h>

// GAT_30039001268364: 3-layer GAT + BN + residual + mean-pool + MLP on MI355X.
// Runtime-adaptive input dtypes (f32-vs-bf16, int64-vs-int32, per-wave ballot probe).
// R10: residual stream h kept in bf16 only (g_hb); scatter loads src post-check;
// convpar folded into convx.

#define NN   50000
#define NE   800000
#define NET  (NE + NN)
#define HD   128
#define NG   64
#define NB   196          // ceil(NN/256)
#define NBN  391          // ceil(NN/128)  — BN stats blocks
#define NCH  20           // pool chunks per graph
#define NTILE 3321        // ceil(NET/256) — edge tiles
#define PSZ  6250         // dst-partition size (8 partitions)

typedef unsigned short u16;
typedef __attribute__((ext_vector_type(8))) short short8;
typedef __attribute__((ext_vector_type(4))) float f32x4;

// ---- canonical parameter pool offsets (bf16 elements) ----
#define O_WEMB 0
#define O_BEMB 16384
#define O_CW   16512
#define O_CAS  49280
#define O_CAD  49536
#define O_CB   49792
#define O_C2W  50048
#define O_C2AS 66432
#define O_C2AD 66560
#define O_C2B  66688
#define O_BNG  66816
#define O_BNB  67200
#define O_L1W  67584
#define O_L1B  83968
#define O_L2W  84096
#define O_L2B  100480
#define O_L3W  100608
#define O_L3B  101888
#define NPAR   101898

// ---- persistent device scratch ----
__device__ int   g_f32flag;
__device__ __align__(16) u16 g_x [NN*HD];
__device__ __align__(16) u16 g_par[NPAR];
__device__ int   g_src[NE], g_dst[NE], g_batch[NN];
__device__ __align__(16) u16 g_hb[NN*HD];   // residual stream h, bf16 (R10: only copy)
__device__ __align__(16) u16 g_hw[NN*HD];
__device__ __align__(16) u16 g_c[NN*HD];    // conv output, bf16
__device__ float g_asrc[NN*8];
__device__ float g_adst[NN*8];
__device__ int   g_rowptr[NN+1];
__device__ int   g_cursor[NN];
__device__ int   g_bsum[NB], g_boff[NB];
__device__ int   g_csr[NET];
__device__ float g_bnp1[NBN*HD], g_bnp2[NBN*HD];
__device__ float g_scl[HD], g_shf[HD];
__device__ int   g_gcnt[NG], g_goff[NG];
__device__ __align__(16) float g_poolp[NG*NCH*HD];
__device__ __align__(16) u16 g_WT[4][HD*HD];

__device__ __forceinline__ float b2f(u16 u) {
    unsigned v = ((unsigned)u) << 16; float f; __builtin_memcpy(&f, &v, 4); return f;
}
__device__ __forceinline__ u16 f2b(float f) {
    unsigned v; __builtin_memcpy(&v, &f, 4);
    return (u16)((v + 0x7fffu + ((v >> 16) & 1u)) >> 16);   // RNE
}

// wave-uniform dtype probes (64 fixed samples, ballot — deterministic)
__device__ __forceinline__ int probe_f32(const void* xp) {
    const u16* p = (const u16*)xp;
    int ex = (p[threadIdx.x & 63] >> 7) & 0xff;
    return __ballot(ex >= 0x93) != 0ULL;   // |v|>=2^20: impossible for bf16 acts
}
__device__ __forceinline__ int probe_i64(const void* eip) {
    const int* q = (const int*)eip;
    return __ballot(q[2*(threadIdx.x & 63) + 1] != 0) == 0ULL; // i64: high words 0
}

// intra-block inclusive scan (256 threads = 4 waves), shuffle-based
__device__ __forceinline__ int block_incl_scan(int v, int* lds4) {
    int t = threadIdx.x, lane = t & 63, w = t >> 6;
    #pragma unroll
    for (int d = 1; d < 64; d <<= 1) {
        int o = __shfl_up(v, d);
        if (lane >= d) v += o;
    }
    if (lane == 63) lds4[w] = v;
    __syncthreads();
    if (w == 0 && lane < 4) {
        int s = lds4[lane];
        #pragma unroll
        for (int d = 1; d < 4; d <<= 1) {
            int o = __shfl_up(s, d);
            if (lane >= d) s += o;
        }
        lds4[lane] = s;
    }
    __syncthreads();
    if (w > 0) v += lds4[w-1];
    return v;
}

// ---- canonicalize x + params (+ cursor init + flag publish) ----
struct P18 { const void* p[18]; int off[18]; int n[18]; };
__global__ void k_convx(const void* xp, P18 a) {    // grid 6250 x 256
    int gi = blockIdx.x*256 + threadIdx.x;
    int f32 = probe_f32(xp);
    if (gi == 0) g_f32flag = f32;
    if (gi < NN) g_cursor[gi] = 1;           // self-loop pre-count
    int i = gi*4;
    if (f32) {
        float4 v = *(const float4*)((const float*)xp + i);
        ushort4 o = { f2b(v.x), f2b(v.y), f2b(v.z), f2b(v.w) };
        *(ushort4*)&g_x[i] = o;
    } else {
        *(ushort4*)&g_x[i] = *(const ushort4*)((const u16*)xp + i);
    }
    if (blockIdx.x < 64) {                   // folded k_convpar
        for (int t = 0; t < 18; ++t) {
            const void* s = a.p[t]; int off = a.off[t], n = a.n[t];
            for (int j = blockIdx.x*256 + threadIdx.x; j < n; j += 64*256)
                g_par[off+j] = f32 ? f2b(((const float*)s)[j]) : ((const u16*)s)[j];
        }
    }
}
__global__ void k_convidx(const void* ei, const void* ba) {   // + fused edge count
    int i64 = probe_i64(ei);
    int e = blockIdx.x*256 + threadIdx.x;
    if (e < NE) {
        int s, d;
        if (i64) { s = (int)((const long long*)ei)[e]; d = (int)((const long long*)ei)[NE + e]; }
        else     { s = ((const int*)ei)[e];            d = ((const int*)ei)[NE + e]; }
        g_src[e] = s; g_dst[e] = d;
        atomicAdd(&g_cursor[d], 1);
    }
    if (e < NN)
        g_batch[e] = i64 ? (int)((const long long*)ba)[e] : ((const int*)ba)[e];
}

// ---- hierarchical exclusive scan of degree counts ----
__global__ void k_blocksum() {
    int i = blockIdx.x*256 + threadIdx.x;
    int v = (i < NN) ? g_cursor[i] : 0;
    #pragma unroll
    for (int d = 32; d; d >>= 1) v += __shfl_down(v, d);
    __shared__ int lds[4];
    if ((threadIdx.x & 63) == 0) lds[threadIdx.x >> 6] = v;
    __syncthreads();
    if (threadIdx.x == 0) g_bsum[blockIdx.x] = lds[0]+lds[1]+lds[2]+lds[3];
}
// ---- merged small ops: weight transposes (0-255), scan (256), graph offsets (257) ----
__global__ void k_misc() {
    int b = blockIdx.x;
    if (b < 256) {
        int which = b >> 6;
        int poff = which==0 ? O_WEMB : which==1 ? O_CW : which==2 ? (O_CW+16384) : O_C2W;
        int idx = (b & 63)*256 + threadIdx.x;
        int n = idx >> 7, k = idx & 127;
        g_WT[which][n*HD + k] = g_par[poff + k*HD + n];
    } else if (b == 256) {
        __shared__ int lds[4];
        int t = threadIdx.x;
        int v = (t < NB) ? g_bsum[t] : 0;
        int incl = block_incl_scan(v, lds);
        if (t < NB) g_boff[t] = incl - v;     // exclusive
    } else {
        __shared__ int off[NG+1];
        int g = threadIdx.x;
        if (g <= NG) {
            int lo = 0, hi = NN;
            while (lo < hi) { int mid = (lo+hi) >> 1; if (g_batch[mid] < g) lo = mid+1; else hi = mid; }
            off[g] = lo;
        }
        __syncthreads();
        if (g < NG) { g_goff[g] = off[g]; g_gcnt[g] = off[g+1] - off[g]; }
    }
}
__global__ void k_downsweep() {
    __shared__ int lds[4];
    int i = blockIdx.x*256 + threadIdx.x;
    int c = (i < NN) ? g_cursor[i] : 0;
    int incl = block_incl_scan(c, lds);
    int base = g_boff[blockIdx.x];
    if (i < NN) {
        g_rowptr[i+1] = base + incl;
        g_cursor[i]   = base + incl - c;  // exclusive start = scatter cursor
    }
    if (i == 0) g_rowptr[0] = 0;
}

// ---- scatter, XCD-affine dst partitioning; src loaded only post-check ----
__global__ void k_scatter() {   // grid NTILE*8
    int part = blockIdx.x & 7;
    int e = (blockIdx.x >> 3)*256 + threadIdx.x;
    if (e >= NET) return;
    int d = (e < NE) ? g_dst[e] : e - NE;
    if (d / PSZ != part) return;
    int s = (e < NE) ? g_src[e] : d;
    int pos = atomicAdd(&g_cursor[d], 1);
    g_csr[pos] = s;
}

// ---- GEMM + fused BN-apply prologue + fused attention-logit epilogue ----
// bnfuse: A rows computed on the fly as h' = relu(c*scl+shf) + h (bf16 streams),
// written back to g_hb; each row element touched by exactly one lane (clamped
// duplicate rows write identical values, benign).
// asoff>=0: a_src/a_dst per row via m16-group shuffle reduction (head = ct).
__global__ __launch_bounds__(256) void k_gemm(int asel, int wsel, int biasoff,
                                              int outmode, int nrows,
                                              int asoff, int adoff, int heads,
                                              int bnfuse) {
    __shared__ __align__(16) u16 wt[HD*136];
    __shared__ float s_scl[HD], s_shf[HD];
    const u16* A = asel ? g_hb : g_x;
    const u16* WTg = g_WT[wsel];
    int t = threadIdx.x;
    #pragma unroll
    for (int i = 0; i < 8; ++i) {
        int e = (t + i*256) * 8;
        int n = e >> 7, k = e & 127;
        *(uint4*)&wt[n*136 + k] = *(const uint4*)&WTg[e];
    }
    if (bnfuse && t < HD) { s_scl[t] = g_scl[t]; s_shf[t] = g_shf[t]; }
    __syncthreads();
    int lane = t & 63, wave = t >> 6;
    int m16 = lane & 15, q = lane >> 4;
    int row0 = blockIdx.x*128 + wave*32;
    f32x4 acc[2][8];
    #pragma unroll
    for (int a = 0; a < 2; ++a)
        #pragma unroll
        for (int b = 0; b < 8; ++b) acc[a][b] = (f32x4){0.f,0.f,0.f,0.f};
    #pragma unroll
    for (int kc = 0; kc < 4; ++kc) {
        short8 af[2];
        #pragma unroll
        for (int rt = 0; rt < 2; ++rt) {
            int r = row0 + rt*16 + m16; if (r > nrows-1) r = nrows-1;
            int base = r*HD + kc*32 + q*8;
            if (bnfuse) {
                short8 cv = *(const short8*)&g_c[base];
                short8 hv = *(const short8*)&g_hb[base];
                #pragma unroll
                for (int k2 = 0; k2 < 8; ++k2) {
                    int ch = kc*32 + q*8 + k2;
                    float v = fmaxf(b2f((u16)cv[k2])*s_scl[ch] + s_shf[ch], 0.f)
                              + b2f((u16)hv[k2]);
                    af[rt][k2] = (short)f2b(v);
                }
                *(short8*)&g_hb[base] = af[rt];
            } else {
                af[rt] = *(const short8*)&A[base];
            }
        }
        #pragma unroll
        for (int ct = 0; ct < 8; ++ct) {
            short8 bf = *(const short8*)&wt[(ct*16 + m16)*136 + kc*32 + q*8];
            acc[0][ct] = __builtin_amdgcn_mfma_f32_16x16x32_bf16(af[0], bf, acc[0][ct], 0,0,0);
            acc[1][ct] = __builtin_amdgcn_mfma_f32_16x16x32_bf16(af[1], bf, acc[1][ct], 0,0,0);
        }
    }
    // C/D layout: col = lane&15, row = q*4 + reg
    #pragma unroll
    for (int rt = 0; rt < 2; ++rt)
        #pragma unroll
        for (int reg = 0; reg < 4; ++reg) {
            int r = row0 + rt*16 + q*4 + reg;
            if (r < nrows) {
                #pragma unroll
                for (int ct = 0; ct < 8; ++ct) {
                    int c = ct*16 + m16;
                    float v = acc[rt][ct][reg];
                    if (biasoff >= 0) v += b2f(g_par[biasoff + c]);
                    if (outmode == 0) g_hb[r*HD+c] = f2b(v);
                    else              g_hw[r*HD+c] = f2b(v);
                }
            }
        }
    if (asoff >= 0) {
        #pragma unroll
        for (int rt = 0; rt < 2; ++rt)
            #pragma unroll
            for (int reg = 0; reg < 4; ++reg) {
                float v[8], u[8];
                #pragma unroll
                for (int ct = 0; ct < 8; ++ct) {
                    float w = acc[rt][ct][reg];
                    v[ct] = w * b2f(g_par[asoff + ct*16 + m16]);
                    u[ct] = w * b2f(g_par[adoff + ct*16 + m16]);
                }
                #pragma unroll
                for (int d = 1; d < 16; d <<= 1)
                    #pragma unroll
                    for (int ct = 0; ct < 8; ++ct) {
                        v[ct] += __shfl_xor(v[ct], d);
                        u[ct] += __shfl_xor(u[ct], d);
                    }
                int r = row0 + rt*16 + q*4 + reg;
                if (m16 == 0 && r < nrows) {
                    if (heads == 8) {
                        #pragma unroll
                        for (int h = 0; h < 8; ++h) {
                            g_asrc[r*8 + h] = v[h];
                            g_adst[r*8 + h] = u[h];
                        }
                    } else {
                        float sv = 0.f, su = 0.f;
                        #pragma unroll
                        for (int ct = 0; ct < 8; ++ct) { sv += v[ct]; su += u[ct]; }
                        g_asrc[r] = sv; g_adst[r] = su;
                    }
                }
            }
    }
}

// ---- segment softmax + aggregate: one wave per dst node, 8/4/1 edge batching ----
__global__ __launch_bounds__(256) void k_flash(int boff, int heads, int hs) {
    int node = blockIdx.x*4 + (threadIdx.x >> 6);
    int lane = threadIdx.x & 63;
    int c0 = lane*2;
    int head = c0 >> hs;
    float ad = g_adst[node*heads + head];
    int beg = g_rowptr[node], end = g_rowptr[node+1];
    float l = 0.f, o0 = 0.f, o1 = 0.f;
    int j = beg;
    for (; j + 8 <= end; j += 8) {
        int s[8]; float av[8]; unsigned w[8];
        #pragma unroll
        for (int k = 0; k < 8; ++k) s[k] = g_csr[j+k];
        #pragma unroll
        for (int k = 0; k < 8; ++k) av[k] = g_asrc[s[k]*heads + head];
        #pragma unroll
        for (int k = 0; k < 8; ++k) w[k] = *(const unsigned*)&g_hw[s[k]*HD + c0];
        #pragma unroll
        for (int k = 0; k < 8; ++k) {
            float e = av[k] + ad;
            e = fmaxf(e, 0.2f*e);
            float p = __expf(fminf(e, 30.f));
            l  += p;
            o0 += p*b2f((u16)(w[k] & 0xffff));
            o1 += p*b2f((u16)(w[k] >> 16));
        }
    }
    for (; j + 4 <= end; j += 4) {
        int s[4]; float av[4]; unsigned w[4];
        #pragma unroll
        for (int k = 0; k < 4; ++k) s[k] = g_csr[j+k];
        #pragma unroll
        for (int k = 0; k < 4; ++k) av[k] = g_asrc[s[k]*heads + head];
        #pragma unroll
        for (int k = 0; k < 4; ++k) w[k] = *(const unsigned*)&g_hw[s[k]*HD + c0];
        #pragma unroll
        for (int k = 0; k < 4; ++k) {
            float e = av[k] + ad;
            e = fmaxf(e, 0.2f*e);
            float p = __expf(fminf(e, 30.f));
            l  += p;
            o0 += p*b2f((u16)(w[k] & 0xffff));
            o1 += p*b2f((u16)(w[k] >> 16));
        }
    }
    for (; j < end; ++j) {
        int s = g_csr[j];
        float e = g_asrc[s*heads + head] + ad;
        e = fmaxf(e, 0.2f*e);
        float p = __expf(fminf(e, 30.f));
        unsigned w = *(const unsigned*)&g_hw[s*HD + c0];
        l  += p;
        o0 += p*b2f((u16)(w & 0xffff));
        o1 += p*b2f((u16)(w >> 16));
    }
    float inv = 1.f/l;                       // l>0: self-loop guarantees >=1 edge
    ushort2 o = { f2b(o0*inv + b2f(g_par[boff + c0])),
                  f2b(o1*inv + b2f(g_par[boff + c0 + 1])) };
    *(ushort2*)&g_c[node*HD + c0] = o;       // bf16 store
}

// ---- BatchNorm: per-block partials + parallel reduce ----
__global__ void k_bnstats() {
    int t = threadIdx.x; int ch = t & 127, r0 = t >> 7;
    int base = blockIdx.x*128;
    float s = 0.f, q = 0.f;
    for (int i = r0; i < 128; i += 2) {
        int n = base + i;
        if (n < NN) { float v = b2f(g_c[n*HD + ch]); s += v; q += v*v; }
    }
    __shared__ float sS[256], sQ[256];
    sS[t] = s; sQ[t] = q; __syncthreads();
    if (t < 128) {
        g_bnp1[blockIdx.x*HD + t] = sS[t] + sS[t+128];
        g_bnp2[blockIdx.x*HD + t] = sQ[t] + sQ[t+128];
    }
}
__global__ void k_bnfinal(int goff, int boff) {   // 128 blocks x 64
    int ch = blockIdx.x, t = threadIdx.x;
    float s = 0.f, q = 0.f;
    for (int b = t; b < NBN; b += 64) { s += g_bnp1[b*HD + ch]; q += g_bnp2[b*HD + ch]; }
    #pragma unroll
    for (int d = 32; d; d >>= 1) { s += __shfl_down(s, d); q += __shfl_down(q, d); }
    if (t == 0) {
        float mean = s / (float)NN;
        float var  = fmaxf(q / (float)NN - mean*mean, 0.f);
        float sc = b2f(g_par[goff + ch]) * rsqrtf(var + 1e-5f);
        g_scl[ch] = sc;
        g_shf[ch] = b2f(g_par[boff + ch]) - mean*sc;
    }
}

// ---- mean pool, stage 1 + fused layer-2 BN/ReLU/residual (bf16 streams) ----
__global__ void k_pool() {
    int g = blockIdx.x / NCH, c = blockIdx.x - g*NCH;
    int cnt = g_gcnt[g], off = g_goff[g];
    int step = (cnt + NCH - 1) / NCH;
    int r0 = c*step, r1 = min(cnt, r0 + step);
    int t = threadIdx.x;
    int ch = (t & 31) * 4;
    int rr = t >> 5;
    float sc0 = g_scl[ch], sc1 = g_scl[ch+1], sc2 = g_scl[ch+2], sc3 = g_scl[ch+3];
    float sf0 = g_shf[ch], sf1 = g_shf[ch+1], sf2 = g_shf[ch+2], sf3 = g_shf[ch+3];
    float4 s = {0.f,0.f,0.f,0.f};
    for (int i = r0 + rr; i < r1; i += 8) {
        int base = (off + i)*HD + ch;
        ushort4 cv = *(const ushort4*)&g_c[base];
        ushort4 hv = *(const ushort4*)&g_hb[base];
        s.x += fmaxf(b2f(cv.x)*sc0 + sf0, 0.f) + b2f(hv.x);
        s.y += fmaxf(b2f(cv.y)*sc1 + sf1, 0.f) + b2f(hv.y);
        s.z += fmaxf(b2f(cv.z)*sc2 + sf2, 0.f) + b2f(hv.z);
        s.w += fmaxf(b2f(cv.w)*sc3 + sf3, 0.f) + b2f(hv.w);
    }
    __shared__ float4 sh[256];
    sh[t] = s; __syncthreads();
    if (t < 32) {
        float4 a = sh[t];
        #pragma unroll
        for (int k = 1; k < 8; ++k) {
            float4 b = sh[t + k*32];
            a.x += b.x; a.y += b.y; a.z += b.z; a.w += b.w;
        }
        *(float4*)&g_poolp[(g*NCH + c)*HD + ch] = a;
    }
}

// ---- fused head: pool-reduce + lin1 + lin2 + lin3, one block per graph ----
__global__ void k_head(void* outB) {
    __shared__ float pl[HD], h1[HD], h2[HD];
    int g = blockIdx.x, t = threadIdx.x;   // 128 threads
    float s = 0.f;
    for (int c = 0; c < NCH; ++c) s += g_poolp[(g*NCH + c)*HD + t];
    pl[t] = s / fmaxf((float)g_gcnt[g], 1.f);
    __syncthreads();
    float acc = b2f(g_par[O_L1B + t]);
    for (int k = 0; k < HD; ++k) acc += pl[k] * b2f(g_par[O_L1W + k*HD + t]);
    h1[t] = fmaxf(acc, 0.f);
    __syncthreads();
    acc = b2f(g_par[O_L2B + t]);
    for (int k = 0; k < HD; ++k) acc += h1[k] * b2f(g_par[O_L2W + k*HD + t]);
    h2[t] = fmaxf(acc, 0.f);
    __syncthreads();
    if (t < 10) {
        acc = b2f(g_par[O_L3B + t]);
        for (int k = 0; k < HD; ++k) acc += h2[k] * b2f(g_par[O_L3W + k*10 + t]);
        if (g_f32flag) ((float*)outB)[g*10 + t] = acc;
        else           ((u16*)outB)[g*10 + t] = f2b(acc);
    }
}

extern "C" void kernel_launch(void* const* d_in, const int* in_sizes, int n_in,
                              void* d_out, int out_size, void* d_ws, size_t ws_size,
                              hipStream_t stream) {
    const void* x     = d_in[0];
    const void* ei    = d_in[1];
    const void* batch = d_in[3];

    P18 a;
    const int srcidx[18] = {4,5,6,7,8,9,10,11,12,13,14,15,16,17,18,19,20,21};
    const int offs[18] = {O_WEMB,O_BEMB,O_CW,O_CAS,O_CAD,O_CB,O_C2W,O_C2AS,O_C2AD,
                          O_C2B,O_BNG,O_BNB,O_L1W,O_L1B,O_L2W,O_L2B,O_L3W,O_L3B};
    const int lens[18] = {16384,128,32768,256,256,256,16384,128,128,128,384,384,
                          16384,128,16384,128,1280,10};
    for (int t = 0; t < 18; ++t) { a.p[t] = d_in[srcidx[t]]; a.off[t] = offs[t]; a.n[t] = lens[t]; }

    k_convx<<<6250, 256, 0, stream>>>(x, a);         // x + params + cursor + flag
    k_convidx<<<3125, 256, 0, stream>>>(ei, batch);  // + edge-count atomics

    k_blocksum<<<NB, 256, 0, stream>>>();
    k_misc<<<258, 256, 0, stream>>>();               // transpose + scanb + gidx
    k_downsweep<<<NB, 256, 0, stream>>>();
    k_scatter<<<NTILE*8, 256, 0, stream>>>();        // XCD-affine partitions

    // embedding: h = x @ W_emb + b_emb  (writes g_hb bf16)
    k_gemm<<<391, 256, 0, stream>>>(0, 0, O_BEMB, 0, NN, -1, -1, 0, 0);

    for (int L = 0; L < 3; ++L) {
        int heads = (L < 2) ? 8 : 1;
        int hs    = (L < 2) ? 4 : 7;
        int as    = (L < 2) ? O_CAS + L*128 : O_C2AS;
        int ad    = (L < 2) ? O_CAD + L*128 : O_C2AD;
        int cb    = (L < 2) ? O_CB  + L*128 : O_C2B;
        // L>0: BN(L-1)+ReLU+residual fused into A-prologue (scl/shf hold L-1)
        k_gemm<<<391, 256, 0, stream>>>(1, L+1, -1, 1, NN, as, ad, heads, L > 0 ? 1 : 0);
        k_flash<<<12500, 256, 0, stream>>>(cb, heads, hs);
        k_bnstats<<<NBN, 256, 0, stream>>>();
        k_bnfinal<<<128, 64, 0, stream>>>(O_BNG + L*HD, O_BNB + L*HD);
    }

    k_pool<<<NG*NCH, 256, 0, stream>>>();            // + fused layer-2 BN/residual
    k_head<<<NG, 128, 0, stream>>>(d_out);
}